// Round 5
// baseline (2092.653 us; speedup 1.0000x reference)
//
#include <hip/hip_runtime.h>
#include <hip/hip_bf16.h>
#include <cstdint>
#include <cstddef>
#include <cmath>

typedef unsigned short u16;
typedef unsigned char  u8;
typedef unsigned int   u32;
typedef __attribute__((ext_vector_type(8))) short short8;   // 8 bf16 MFMA frag
typedef __attribute__((ext_vector_type(4))) float f32x4;    // MFMA accumulator
typedef __attribute__((ext_vector_type(4))) u16 u16x4;

#define CCH 256
#define HWP 6400   // 80*80

__device__ __forceinline__ u16 f2bf(float f) {
  u32 u = __float_as_uint(f);
  u = (u + 0x7FFFu + ((u >> 16) & 1u)) >> 16;   // RNE
  return (u16)u;
}
__device__ __forceinline__ float bf2f(u16 h) { return __uint_as_float(((u32)h) << 16); }
__device__ __forceinline__ void split3(float v, u16& h, u16& m, u16& l) {
  h = f2bf(v); float r = v - bf2f(h);
  m = f2bf(r); l = f2bf(r - bf2f(m));
}
__device__ __forceinline__ void gl_lds16(const void* g, void* l) {
  __builtin_amdgcn_global_load_lds((const __attribute__((address_space(1))) unsigned int*)g,
                                   (__attribute__((address_space(3))) unsigned int*)l,
                                   16, 0, 0);
}

// ---------------------------------------------------------------------------
// Fold BN into conv weights; emit 3-way split bf16 weights + fp32 biases.
// ---------------------------------------------------------------------------
__global__ __launch_bounds__(256) void fold_weights(
    const float* __restrict__ w1, const float* __restrict__ w2,
    const float* __restrict__ bnp,
    u16* __restrict__ w1h, u16* __restrict__ w1m, u16* __restrict__ w1l,
    u16* __restrict__ w2h, u16* __restrict__ w2m, u16* __restrict__ w2l,
    float* __restrict__ b0f, float* __restrict__ b2f)
{
  int i = blockIdx.x >> 8, o = blockIdx.x & 255, c = threadIdx.x;
  const float* bp = bnp + i * 3072;
  double g0 = bp[0 + o],    be0 = bp[256 + o],  m0 = bp[512 + o],  v0 = bp[768 + o];
  double g1 = bp[1024 + o], be1 = bp[1280 + o], m1 = bp[1536 + o], v1 = bp[1792 + o];
  double g2 = bp[2048 + o], be2 = bp[2304 + o], m2 = bp[2560 + o], v2 = bp[2816 + o];
  double s0 = g0 / sqrt(v0 + 1e-5);
  double s1 = g1 / sqrt(v1 + 1e-5);
  double s2 = g2 / sqrt(v2 + 1e-5);
  size_t ro = (size_t)(i * 256 + o) * 256;
  float wa = (float)(s0 * (double)w1[ro + c]);
  float wb = (float)(s1 * s2 * (double)w2[ro + c]);
  u16 h, m, l;
  split3(wa, h, m, l); w1h[ro + c] = h; w1m[ro + c] = m; w1l[ro + c] = l;
  split3(wb, h, m, l); w2h[ro + c] = h; w2m[ro + c] = m; w2l[ro + c] = l;
  if (c == 0) {
    b0f[i * 256 + o] = (float)(be0 - m0 * s0);
    b2f[i * 256 + o] = (float)(s2 * (be1 - m1 * s1) + be2 - m2 * s2);
  }
}

// ---------------------------------------------------------------------------
// Head spike + transpose: x[b][c][p] fp32 -> xs[z][p][c] u8 {0,1} (exact)
// ---------------------------------------------------------------------------
__global__ __launch_bounds__(256) void head_spike(
    const float* __restrict__ x, u8* __restrict__ xs, int b0)
{
  __shared__ u8 tile[64][68];
  int z = blockIdx.z, c0 = blockIdx.y << 6, p0 = blockIdx.x << 6;
  int tid = threadIdx.x;
  const float* xb = x + ((size_t)(b0 + z) * CCH + c0) * HWP + p0;
#pragma unroll
  for (int j = 0; j < 16; ++j) {
    int idx = j * 256 + tid;
    int cl = idx >> 6, pl = idx & 63;
    tile[pl][cl] = (xb[(size_t)cl * HWP + pl] >= 2.0f) ? 1 : 0;
  }
  __syncthreads();
#pragma unroll
  for (int j = 0; j < 4; ++j) {
    int idx = j * 256 + tid;
    int row = idx >> 4, c4 = (idx & 15) << 2;
    *(uchar4*)(xs + ((size_t)z * HWP + p0 + row) * CCH + c0 + c4) =
        *(const uchar4*)&tile[row][c4];
  }
}

// ---------------------------------------------------------------------------
// u8 transpose: in[z][c][p] -> out[b0+z][p][c]   (s after attention)
// ---------------------------------------------------------------------------
__global__ __launch_bounds__(256) void transpose_s(
    const u8* __restrict__ in, u8* __restrict__ out, int b0)
{
  __shared__ u8 tile[64][68];
  int z = blockIdx.z, c0 = blockIdx.y << 6, p0 = blockIdx.x << 6;
  int tid = threadIdx.x;
#pragma unroll
  for (int j = 0; j < 4; ++j) {
    int idx = j * 256 + tid;
    int cl = idx >> 4, p4 = (idx & 15) << 2;
    uchar4 v = *(const uchar4*)(in + ((size_t)z * CCH + c0 + cl) * HWP + p0 + p4);
    tile[p4 + 0][cl] = v.x; tile[p4 + 1][cl] = v.y;
    tile[p4 + 2][cl] = v.z; tile[p4 + 3][cl] = v.w;
  }
  __syncthreads();
#pragma unroll
  for (int j = 0; j < 4; ++j) {
    int idx = j * 256 + tid;
    int row = idx >> 4, c4 = (idx & 15) << 2;
    *(uchar4*)(out + ((size_t)(b0 + z) * HWP + p0 + row) * CCH + c0 + c4) =
        *(const uchar4*)&tile[row][c4];
  }
}

// ---------------------------------------------------------------------------
// GEMM1 v2: T1 = bias + act(binary u8) x W(3-split), 128x128 tile, K=256.
// W fragments read DIRECT from global (L2-resident, 384 KB/dispatch; a wave's
// lr lanes consume one contiguous 64B line per row). Net swizzle of the old
// LDS path == natural fragment, so bytes are identical. Only the act
// expansion uses LDS -> barrier carries no DMA drain.
// launch_bounds(256,4): 4 blocks/CU, 800-block grid single-round.
// ---------------------------------------------------------------------------
__global__ __launch_bounds__(256, 4) void gemm1(
    const u8* __restrict__ act, int b0in,
    const u16* __restrict__ WH, const u16* __restrict__ WM, const u16* __restrict__ WL,
    const float* __restrict__ bias, float* __restrict__ T1)
{
  __shared__ alignas(16) u16 As[128 * 40];
  const int tid = threadIdx.x, wave = tid >> 6, lane = tid & 63;
  const int p0 = blockIdx.x * 128, o0 = blockIdx.y * 128, z = blockIdx.z;
  const int wm = (wave >> 1) * 64, wn = (wave & 1) * 64;
  const int lc = lane & 15, lr = lane >> 4;
  const u8* ab = act + ((size_t)(b0in + z) * HWP + p0) * CCH;
  const u16* wht = WH + (size_t)o0 * 256;
  const u16* wmt = WM + (size_t)o0 * 256;
  const u16* wlt = WL + (size_t)o0 * 256;

  f32x4 acc[4][4];
#pragma unroll
  for (int i = 0; i < 4; ++i)
#pragma unroll
    for (int j = 0; j < 4; ++j) acc[i][j] = (f32x4){0.f, 0.f, 0.f, 0.f};

  const int srow = tid >> 1, shalf = tid & 1;

#pragma unroll 1
  for (int kc = 0; kc < 8; ++kc) {
    __syncthreads();
    // expand binary act into As
    uint4 u = *(const uint4*)(ab + (size_t)srow * CCH + kc * 32 + shalf * 16);
    u32 vv[4] = {u.x, u.y, u.z, u.w};
    u32 w[8];
#pragma unroll
    for (int q = 0; q < 4; ++q) {
      u32 v = vv[q];
      w[2 * q]     = ((v & 255u) ? 0x3F80u : 0u) | (((v >> 8) & 255u) ? 0x3F800000u : 0u);
      w[2 * q + 1] = (((v >> 16) & 255u) ? 0x3F80u : 0u) | (((v >> 24) & 255u) ? 0x3F800000u : 0u);
    }
    *(uint4*)&As[srow * 40 + shalf * 16]     = (uint4){w[0], w[1], w[2], w[3]};
    *(uint4*)&As[srow * 40 + shalf * 16 + 8] = (uint4){w[4], w[5], w[6], w[7]};
    __syncthreads();
    short8 af[4];
#pragma unroll
    for (int i = 0; i < 4; ++i)
      af[i] = *(const short8*)&As[(wm + i * 16 + lc) * 40 + lr * 8];
#pragma unroll
    for (int j = 0; j < 4; ++j) {
      int row = wn + j * 16 + lc;
      size_t wo = (size_t)row * 256 + kc * 32 + lr * 8;
      short8 bh = *(const short8*)(wht + wo);
      short8 bm = *(const short8*)(wmt + wo);
      short8 bl = *(const short8*)(wlt + wo);
#pragma unroll
      for (int i = 0; i < 4; ++i) {
        acc[i][j] = __builtin_amdgcn_mfma_f32_16x16x32_bf16(af[i], bl, acc[i][j], 0, 0, 0);
        acc[i][j] = __builtin_amdgcn_mfma_f32_16x16x32_bf16(af[i], bm, acc[i][j], 0, 0, 0);
        acc[i][j] = __builtin_amdgcn_mfma_f32_16x16x32_bf16(af[i], bh, acc[i][j], 0, 0, 0);
      }
    }
  }
  float* tb = T1 + ((size_t)z * HWP + p0) * CCH + o0;
#pragma unroll
  for (int j = 0; j < 4; ++j) {
    int n = wn + j * 16 + lc;
    float bn_ = bias[o0 + n];
#pragma unroll
    for (int i = 0; i < 4; ++i) {
      int m = wm + i * 16 + lr * 4;
#pragma unroll
      for (int r = 0; r < 4; ++r)
        tb[(size_t)(m + r) * CCH + n] = acc[i][j][r] + bn_;
    }
  }
}

// ---------------------------------------------------------------------------
// Depthwise 3x3 SAME: T1[z][p][c] fp32 -> 3-way split bf16 planes (pixel-major).
// ---------------------------------------------------------------------------
__global__ __launch_bounds__(256) void dw3(
    const float* __restrict__ t1, const float* __restrict__ dwk,
    u16* __restrict__ oh, u16* __restrict__ om, u16* __restrict__ ol)
{
  __shared__ float wl[2304];   // [c][9]
  int tid = threadIdx.x;
#pragma unroll
  for (int t = 0; t < 9; ++t) wl[t * 256 + tid] = dwk[t * 256 + tid];
  int c4 = (tid & 63) << 2;
  int pl = tid >> 6;
  int p = blockIdx.x * 4 + pl;
  int z = blockIdx.y;
  int y = p / 80, x = p - y * 80;
  __syncthreads();
  float a0 = 0.f, a1 = 0.f, a2 = 0.f, a3 = 0.f;
  const float* base = t1 + (size_t)z * HWP * CCH;
  const float* wc = &wl[c4 * 9];
#pragma unroll
  for (int dy = -1; dy <= 1; ++dy) {
    int yy = y + dy;
    bool vy = (unsigned)yy < 80u;
#pragma unroll
    for (int dx = -1; dx <= 1; ++dx) {
      int xx = x + dx;
      if (vy && (unsigned)xx < 80u) {
        float4 v = *(const float4*)(base + (size_t)(yy * 80 + xx) * CCH + c4);
        int t = (dy + 1) * 3 + (dx + 1);
        a0 += wc[t]      * v.x;
        a1 += wc[9 + t]  * v.y;
        a2 += wc[18 + t] * v.z;
        a3 += wc[27 + t] * v.w;
      }
    }
  }
  u16 h0, m0, l0, h1, m1, l1, h2, m2, l2, h3, m3, l3;
  split3(a0, h0, m0, l0);
  split3(a1, h1, m1, l1);
  split3(a2, h2, m2, l2);
  split3(a3, h3, m3, l3);
  u16x4 vh, vm, vlo;
  vh.x = h0; vh.y = h1; vh.z = h2; vh.w = h3;
  vm.x = m0; vm.y = m1; vm.z = m2; vm.w = m3;
  vlo.x = l0; vlo.y = l1; vlo.z = l2; vlo.w = l3;
  size_t addr = ((size_t)z * HWP + p) * CCH + c4;
  *(u16x4*)(oh + addr) = vh;
  *(u16x4*)(om + addr) = vm;
  *(u16x4*)(ol + addr) = vlo;
}

// ---------------------------------------------------------------------------
// GEMM2 v4: out = bias + dwact(3-split) x W2(3-split), 6 MFMA passes, K=256.
//  * A (HBM-streamed) staged via swizzled global_load_lds -- MUST stay LDS
//    (round-3: direct A loads quadrupled HBM via L2 line thrash).
//  * W fragments DIRECT from global: L2-resident (384 KB), lr lanes consume
//    contiguous 64B lines; bytes identical to the old swizzled-LDS path.
//  * LDS 24 KB + launch_bounds(256,4): 4 blocks/CU -> 800 blocks single-round
//    (was 3/CU -> 768 capacity -> 2-round tail).
// MODE 0: fp32 channel-major out[(b0+z)][o][p] + bias
// MODE 1: u8 spike (val >= 2) channel-major
// MODE 2: 3-way split bf16 planes channel-major (bitwise identical values)
// ---------------------------------------------------------------------------
template <int MODE>
__global__ __launch_bounds__(256, 4) void gemm2s(
    const u16* __restrict__ AH, const u16* __restrict__ AM, const u16* __restrict__ AL,
    const u16* __restrict__ WH, const u16* __restrict__ WM, const u16* __restrict__ WL,
    const float* __restrict__ bias, int b0,
    float* __restrict__ outF, u8* __restrict__ outB,
    u16* __restrict__ outH, u16* __restrict__ outM, u16* __restrict__ outL)
{
  __shared__ alignas(16) u16 LAH[4096];
  __shared__ alignas(16) u16 LAM[4096];
  __shared__ alignas(16) u16 LAL[4096];
  const int tid = threadIdx.x, wave = tid >> 6, lane = tid & 63;
  const int p0 = blockIdx.x * 128, o0 = blockIdx.y * 128, z = blockIdx.z;
  const int wm = (wave >> 1) * 64, wn = (wave & 1) * 64;
  const int lc = lane & 15, lr = lane >> 4;
  const char* ahb = (const char*)(AH + ((size_t)z * HWP + p0) * 256);
  const char* amb = (const char*)(AM + ((size_t)z * HWP + p0) * 256);
  const char* alb = (const char*)(AL + ((size_t)z * HWP + p0) * 256);
  const u16* wht = WH + (size_t)o0 * 256;
  const u16* wmt = WM + (size_t)o0 * 256;
  const u16* wlt = WL + (size_t)o0 * 256;

  f32x4 acc[4][4];
#pragma unroll
  for (int i = 0; i < 4; ++i)
#pragma unroll
    for (int j = 0; j < 4; ++j) acc[i][j] = (f32x4){0.f, 0.f, 0.f, 0.f};

#pragma unroll 1
  for (int kc = 0; kc < 8; ++kc) {
    const int kof = kc * 64;
#pragma unroll
    for (int t = 0; t < 2; ++t) {
      int li = t * 256 + tid;
      int row = li >> 2, ch = li & 3;
      int chp = (ch - row - (row >> 2)) & 3;   // swizzled source granule
      size_t so = (size_t)row * 512 + kof + chp * 16;
      int base = (t * 256 + wave * 64) * 8;
      gl_lds16(ahb + so, &LAH[base]);
      gl_lds16(amb + so, &LAM[base]);
      gl_lds16(alb + so, &LAL[base]);
    }
    __syncthreads();
    short8 afH[4], afM[4], afL[4];
#pragma unroll
    for (int i = 0; i < 4; ++i) {
      int row = wm + i * 16 + lc;
      int o = row * 32 + ((lr + lc + (lc >> 2)) & 3) * 8;
      afH[i] = *(const short8*)&LAH[o];
      afM[i] = *(const short8*)&LAM[o];
      afL[i] = *(const short8*)&LAL[o];
    }
#pragma unroll
    for (int j = 0; j < 4; ++j) {
      int row = wn + j * 16 + lc;
      size_t wo = (size_t)row * 256 + kc * 32 + lr * 8;
      short8 bh = *(const short8*)(wht + wo);
      short8 bm = *(const short8*)(wmt + wo);
      short8 bl = *(const short8*)(wlt + wo);
#pragma unroll
      for (int i = 0; i < 4; ++i) {
        acc[i][j] = __builtin_amdgcn_mfma_f32_16x16x32_bf16(afM[i], bm, acc[i][j], 0, 0, 0);
        acc[i][j] = __builtin_amdgcn_mfma_f32_16x16x32_bf16(afL[i], bh, acc[i][j], 0, 0, 0);
        acc[i][j] = __builtin_amdgcn_mfma_f32_16x16x32_bf16(afH[i], bl, acc[i][j], 0, 0, 0);
        acc[i][j] = __builtin_amdgcn_mfma_f32_16x16x32_bf16(afM[i], bh, acc[i][j], 0, 0, 0);
        acc[i][j] = __builtin_amdgcn_mfma_f32_16x16x32_bf16(afH[i], bm, acc[i][j], 0, 0, 0);
        acc[i][j] = __builtin_amdgcn_mfma_f32_16x16x32_bf16(afH[i], bh, acc[i][j], 0, 0, 0);
      }
    }
    __syncthreads();   // all waves done reading LA before next-step DMA overwrites
  }
  // Epilogue: channel-major, m = pixel, n = out-channel.
#pragma unroll
  for (int j = 0; j < 4; ++j) {
    int n = o0 + wn + j * 16 + lc;
    float bn_ = bias[n];
    size_t rowb = ((size_t)(b0 + z) * CCH + n) * HWP + p0;
#pragma unroll
    for (int i = 0; i < 4; ++i) {
      int m = wm + i * 16 + lr * 4;
      if (MODE == 0) {
        float4 o;
        o.x = acc[i][j][0] + bn_; o.y = acc[i][j][1] + bn_;
        o.z = acc[i][j][2] + bn_; o.w = acc[i][j][3] + bn_;
        *(float4*)(outF + rowb + m) = o;
      } else if (MODE == 1) {
        uchar4 o;
        o.x = (acc[i][j][0] + bn_ >= 2.0f) ? 1 : 0;
        o.y = (acc[i][j][1] + bn_ >= 2.0f) ? 1 : 0;
        o.z = (acc[i][j][2] + bn_ >= 2.0f) ? 1 : 0;
        o.w = (acc[i][j][3] + bn_ >= 2.0f) ? 1 : 0;
        *(uchar4*)(outB + rowb + m) = o;
      } else {
        u16x4 vh, vm2, vl2;
#pragma unroll
        for (int r = 0; r < 4; ++r) {
          u16 hh, mm, ll;
          split3(acc[i][j][r] + bn_, hh, mm, ll);
          vh[r] = hh; vm2[r] = mm; vl2[r] = ll;
        }
        *(u16x4*)(outH + rowb + m) = vh;
        *(u16x4*)(outM + rowb + m) = vm2;
        *(u16x4*)(outL + rowb + m) = vl2;
      }
    }
  }
}

// ---------------------------------------------------------------------------
// Attention per (z,c): Q and K arrive PRE-SPLIT (3 bf16 planes each, from
// gemm2s MODE 2) -- no split3 in the staging path at all.
// 320 threads: wave = m-tile. LDS row stride 104 u16 (2-way b128 reads).
// ---------------------------------------------------------------------------
__global__ __launch_bounds__(320) void attn_k(
    const u16* __restrict__ qh_g, const u16* __restrict__ qm_g, const u16* __restrict__ ql_g,
    const u16* __restrict__ kh_g, const u16* __restrict__ km_g, const u16* __restrict__ kl_g,
    const u8* __restrict__ vv, u8* __restrict__ s)
{
  __shared__ alignas(16) u16 L[24960];   // K 3-split [h'][w]; overlaid by S 3-split [h][h']
  __shared__ alignas(16) u8  VT[8320];   // V^T [u][h'] stride 104
  const int tid = threadIdx.x, wave = tid >> 6, lane = tid & 63;
  const int lc = lane & 15, lr = lane >> 4;
  const size_t off = (size_t)blockIdx.x * HWP;
  u16* KH = L; u16* KM = L + 8320; u16* KL = L + 16640;

  // Hoist Q fragments: row h = wave*16+lc, k-cols w0..w0+7.
  short8 qfr[3][3];  // [kc][h/m/l]
  const int hrow = wave * 16 + lc;
#pragma unroll
  for (int kc = 0; kc < 3; ++kc) {
    int w0 = kc * 32 + lr * 8;
    if (w0 < 80) {
      size_t qo = off + (size_t)hrow * 80 + w0;
      qfr[kc][0] = *(const short8*)(qh_g + qo);
      qfr[kc][1] = *(const short8*)(qm_g + qo);
      qfr[kc][2] = *(const short8*)(ql_g + qo);
    } else {
      qfr[kc][0] = (short8){0, 0, 0, 0, 0, 0, 0, 0};
      qfr[kc][1] = qfr[kc][0];
      qfr[kc][2] = qfr[kc][0];
    }
  }

  // Stage K 3-split planes: 12 granules/row (10 data + 2 zero pad), 80 rows.
#pragma unroll
  for (int t = 0; t < 3; ++t) {
    int g = t * 320 + tid;            // 0..959
    int h = g / 12, wc = g - h * 12;
    int dst = h * 104 + wc * 8;
    if (wc < 10) {
      size_t so = off + (size_t)h * 80 + wc * 8;
      *(short8*)&KH[dst] = *(const short8*)(kh_g + so);
      *(short8*)&KM[dst] = *(const short8*)(km_g + so);
      *(short8*)&KL[dst] = *(const short8*)(kl_g + so);
    } else {
      short8 z8 = (short8){0, 0, 0, 0, 0, 0, 0, 0};
      *(short8*)&KH[dst] = z8; *(short8*)&KM[dst] = z8; *(short8*)&KL[dst] = z8;
    }
  }
  // VT pads (cols 80..95): 80 rows x 4 dwords, exactly 320 threads.
  {
    int row = tid >> 2, qq = tid & 3;
    *(u32*)&VT[row * 104 + 80 + qq * 4] = 0;
  }
  // VT transpose stage: uchar4 reads, byte scatter.
#pragma unroll
  for (int t = 0; t < 5; ++t) {
    int q = t * 320 + tid;            // 0..1599 quads
    int h = q / 20, w4 = (q - h * 20) * 4;
    uchar4 v4 = *(const uchar4*)(vv + off + (size_t)h * 80 + w4);
    VT[(w4 + 0) * 104 + h] = v4.x;
    VT[(w4 + 1) * 104 + h] = v4.y;
    VT[(w4 + 2) * 104 + h] = v4.z;
    VT[(w4 + 3) * 104 + h] = v4.w;
  }
  __syncthreads();

  // Stage 1: S = Q K^T.  m-rows h = wave*16+lc, k = w (pad 96), n = h'.
  f32x4 accS[5];
#pragma unroll
  for (int n = 0; n < 5; ++n) accS[n] = (f32x4){0.f, 0.f, 0.f, 0.f};
  for (int kc = 0; kc < 3; ++kc) {
#pragma unroll
    for (int n = 0; n < 5; ++n) {
      int bo = (n * 16 + lc) * 104 + kc * 32 + lr * 8;
      short8 kh_ = *(const short8*)&KH[bo];
      short8 km_ = *(const short8*)&KM[bo];
      short8 kl_ = *(const short8*)&KL[bo];
      __builtin_amdgcn_s_setprio(1);
      accS[n] = __builtin_amdgcn_mfma_f32_16x16x32_bf16(qfr[kc][0], kl_, accS[n], 0, 0, 0);
      accS[n] = __builtin_amdgcn_mfma_f32_16x16x32_bf16(qfr[kc][2], kh_, accS[n], 0, 0, 0);
      accS[n] = __builtin_amdgcn_mfma_f32_16x16x32_bf16(qfr[kc][1], km_, accS[n], 0, 0, 0);
      accS[n] = __builtin_amdgcn_mfma_f32_16x16x32_bf16(qfr[kc][1], kh_, accS[n], 0, 0, 0);
      accS[n] = __builtin_amdgcn_mfma_f32_16x16x32_bf16(qfr[kc][0], km_, accS[n], 0, 0, 0);
      accS[n] = __builtin_amdgcn_mfma_f32_16x16x32_bf16(qfr[kc][0], kh_, accS[n], 0, 0, 0);
      __builtin_amdgcn_s_setprio(0);
    }
  }
  __syncthreads();   // all K reads done; L becomes S (pads stay zero)
#pragma unroll
  for (int n = 0; n < 5; ++n) {
#pragma unroll
    for (int r = 0; r < 4; ++r) {
      u16 hh, mm, ll; split3(accS[n][r], hh, mm, ll);
      int o = (wave * 16 + lr * 4 + r) * 104 + n * 16 + lc;
      KH[o] = hh; KM[o] = mm; KL[o] = ll;
    }
  }
  __syncthreads();
  // Stage 2: attn = S V ; spike at raw >= 8  (attn*0.125 >= 1)
  f32x4 accA[5];
#pragma unroll
  for (int n = 0; n < 5; ++n) accA[n] = (f32x4){0.f, 0.f, 0.f, 0.f};
  for (int kc = 0; kc < 3; ++kc) {
    int ao = (wave * 16 + lc) * 104 + kc * 32 + lr * 8;
    short8 sh_ = *(const short8*)&KH[ao];
    short8 sm_ = *(const short8*)&KM[ao];
    short8 sl_ = *(const short8*)&KL[ao];
#pragma unroll
    for (int n = 0; n < 5; ++n) {
      const u8* vp = &VT[(n * 16 + lc) * 104 + kc * 32 + lr * 8];
      u32 b0 = *(const u32*)vp;
      u32 b1 = *(const u32*)(vp + 4);
      u32 e0 = ((b0 & 255u) ? 0x3F80u : 0u) | (((b0 >> 8) & 255u) ? 0x3F800000u : 0u);
      u32 e1 = (((b0 >> 16) & 255u) ? 0x3F80u : 0u) | (((b0 >> 24) & 255u) ? 0x3F800000u : 0u);
      u32 e2 = ((b1 & 255u) ? 0x3F80u : 0u) | (((b1 >> 8) & 255u) ? 0x3F800000u : 0u);
      u32 e3 = (((b1 >> 16) & 255u) ? 0x3F80u : 0u) | (((b1 >> 24) & 255u) ? 0x3F800000u : 0u);
      u32 vbw[4] = {e0, e1, e2, e3};
      short8 vb = *(const short8*)vbw;
      __builtin_amdgcn_s_setprio(1);
      accA[n] = __builtin_amdgcn_mfma_f32_16x16x32_bf16(sl_, vb, accA[n], 0, 0, 0);
      accA[n] = __builtin_amdgcn_mfma_f32_16x16x32_bf16(sm_, vb, accA[n], 0, 0, 0);
      accA[n] = __builtin_amdgcn_mfma_f32_16x16x32_bf16(sh_, vb, accA[n], 0, 0, 0);
      __builtin_amdgcn_s_setprio(0);
    }
  }
#pragma unroll
  for (int n = 0; n < 5; ++n)
#pragma unroll
    for (int r = 0; r < 4; ++r)
      s[off + (size_t)(wave * 16 + lr * 4 + r) * 80 + n * 16 + lc] =
          (accA[n][r] >= 8.0f) ? 1 : 0;
}

// ---------------------------------------------------------------------------
extern "C" void kernel_launch(void* const* d_in, const int* in_sizes, int n_in,
                              void* d_out, int out_size, void* d_ws, size_t ws_size,
                              hipStream_t stream)
{
  const float* x   = (const float*)d_in[0];
  const float* w1  = (const float*)d_in[1];
  const float* dwk = (const float*)d_in[2];
  const float* w2  = (const float*)d_in[3];
  const float* bnp = (const float*)d_in[4];
  float* out = (float*)d_out;
  char* ws = (char*)d_ws;

  // Workspace layout (~292 MB total, unchanged size).
  // Branch order per chunk is v -> q -> k so that:
  //   Q planes (78.6 MB) occupy the old QF+KF region (104.9 MB),
  //   K planes overlay T1 (dead after k's dw3) + the QF+KF remainder.
  u16* W1H = (u16*)(ws + 0);
  u16* W1M = (u16*)(ws + 524288);
  u16* W1L = (u16*)(ws + 1048576);
  u16* W2H = (u16*)(ws + 1572864);
  u16* W2M = (u16*)(ws + 2097152);
  u16* W2L = (u16*)(ws + 2621440);
  float* B0F = (float*)(ws + 3145728);
  float* B2F = (float*)(ws + 3149824);
  u8*    SPM = (u8*)(ws + 3153920);          // s pixel-major, full 16 batches
  u8*    XS  = (u8*)(ws + 29368320);         // xs, half-batch chunk
  float* T1  = (float*)(ws + 42475520);      // fp32 branch tmp, half chunk
  u16*   KH_ = (u16*)(ws + 42475520);        // overlays T1 (T1 dead at write time)
  u16*   KM_ = (u16*)(ws + 68689920);
  u16*   QH_ = (u16*)(ws + 94904320);        // old QF region start
  u16*   QM_ = (u16*)(ws + 121118720);
  u16*   QL_ = (u16*)(ws + 147333120);
  u16*   KL_ = (u16*)(ws + 173547520);       // old KF region tail
  u8*    V   = (u8*)(ws + 199761920);        // v binary CM (s_cm in-place)
  u16*   D2H = (u16*)(ws + 212869120);       // dw split hi, pixel-major
  u16*   D2M = (u16*)(ws + 239083520);
  u16*   D2L = (u16*)(ws + 265297920);       // ends 291512320

  dim3 gb(256);
  fold_weights<<<dim3(1024), gb, 0, stream>>>(w1, w2, bnp,
      W1H, W1M, W1L, W2H, W2M, W2L, B0F, B2F);

  for (int c = 0; c < 2; ++c) {
    int b0 = c * 8;
    dim3 gh(100, 4, 8), gg(50, 2, 8), gd(1600, 8);
    head_spike<<<gh, gb, 0, stream>>>(x, XS, b0);
    // v branch (binary spike epilogue) -- first, so T1 is free for K planes later
    gemm1<<<gg, gb, 0, stream>>>(XS, 0, W1H + 2 * 65536, W1M + 2 * 65536, W1L + 2 * 65536,
                                 B0F + 512, T1);
    dw3<<<gd, gb, 0, stream>>>(T1, dwk + 2 * 2304, D2H, D2M, D2L);
    gemm2s<1><<<gg, gb, 0, stream>>>(D2H, D2M, D2L,
                                     W2H + 2 * 65536, W2M + 2 * 65536, W2L + 2 * 65536,
                                     B2F + 512, 0, nullptr, V, nullptr, nullptr, nullptr);
    // q branch -> pre-split planes
    gemm1<<<gg, gb, 0, stream>>>(XS, 0, W1H + 0 * 65536, W1M + 0 * 65536, W1L + 0 * 65536,
                                 B0F + 0, T1);
    dw3<<<gd, gb, 0, stream>>>(T1, dwk + 0 * 2304, D2H, D2M, D2L);
    gemm2s<2><<<gg, gb, 0, stream>>>(D2H, D2M, D2L,
                                     W2H + 0 * 65536, W2M + 0 * 65536, W2L + 0 * 65536,
                                     B2F + 0, 0, nullptr, nullptr, QH_, QM_, QL_);
    // k branch -> pre-split planes (KH_/KM_ overlay T1, which is dead by then)
    gemm1<<<gg, gb, 0, stream>>>(XS, 0, W1H + 1 * 65536, W1M + 1 * 65536, W1L + 1 * 65536,
                                 B0F + 256, T1);
    dw3<<<gd, gb, 0, stream>>>(T1, dwk + 1 * 2304, D2H, D2M, D2L);
    gemm2s<2><<<gg, gb, 0, stream>>>(D2H, D2M, D2L,
                                     W2H + 1 * 65536, W2M + 1 * 65536, W2L + 1 * 65536,
                                     B2F + 256, 0, nullptr, nullptr, KH_, KM_, KL_);
    // attention -> s channel-major (in-place over V), then to pixel-major SPM
    attn_k<<<dim3(2048), dim3(320), 0, stream>>>(QH_, QM_, QL_, KH_, KM_, KL_, V, V);
    transpose_s<<<gh, gb, 0, stream>>>(V, SPM, b0);
  }
  // proj branch -> fp32 d_out (channel-major), chunked to fit T1
  for (int c = 0; c < 2; ++c) {
    int b0 = c * 8;
    dim3 gg(50, 2, 8), gd(1600, 8);
    gemm1<<<gg, gb, 0, stream>>>(SPM, b0, W1H + 3 * 65536, W1M + 3 * 65536, W1L + 3 * 65536,
                                 B0F + 768, T1);
    dw3<<<gd, gb, 0, stream>>>(T1, dwk + 3 * 2304, D2H, D2M, D2L);
    gemm2s<0><<<gg, gb, 0, stream>>>(D2H, D2M, D2L,
                                     W2H + 3 * 65536, W2M + 3 * 65536, W2L + 3 * 65536,
                                     B2F + 768, b0, out, nullptr, nullptr, nullptr, nullptr);
  }
}

// Round 6
// 1600.510 us; speedup vs baseline: 1.3075x; 1.3075x over previous
//
#include <hip/hip_runtime.h>
#include <hip/hip_bf16.h>
#include <cstdint>
#include <cstddef>
#include <cmath>

typedef unsigned short u16;
typedef unsigned char  u8;
typedef unsigned int   u32;
typedef __attribute__((ext_vector_type(8))) short short8;   // 8 bf16 MFMA frag
typedef __attribute__((ext_vector_type(4))) float f32x4;    // MFMA accumulator
typedef __attribute__((ext_vector_type(4))) u16 u16x4;

#define CCH 256
#define HWP 6400   // 80*80

__device__ __forceinline__ u16 f2bf(float f) {
  u32 u = __float_as_uint(f);
  u = (u + 0x7FFFu + ((u >> 16) & 1u)) >> 16;   // RNE
  return (u16)u;
}
__device__ __forceinline__ float bf2f(u16 h) { return __uint_as_float(((u32)h) << 16); }
__device__ __forceinline__ void split3(float v, u16& h, u16& m, u16& l) {
  h = f2bf(v); float r = v - bf2f(h);
  m = f2bf(r); l = f2bf(r - bf2f(m));
}
__device__ __forceinline__ void gl_lds16(const void* g, void* l) {
  __builtin_amdgcn_global_load_lds((const __attribute__((address_space(1))) unsigned int*)g,
                                   (__attribute__((address_space(3))) unsigned int*)l,
                                   16, 0, 0);
}

// ---------------------------------------------------------------------------
// Fold BN into conv weights; emit 3-way split bf16 weights + fp32 biases.
// ---------------------------------------------------------------------------
__global__ __launch_bounds__(256) void fold_weights(
    const float* __restrict__ w1, const float* __restrict__ w2,
    const float* __restrict__ bnp,
    u16* __restrict__ w1h, u16* __restrict__ w1m, u16* __restrict__ w1l,
    u16* __restrict__ w2h, u16* __restrict__ w2m, u16* __restrict__ w2l,
    float* __restrict__ b0f, float* __restrict__ b2f)
{
  int i = blockIdx.x >> 8, o = blockIdx.x & 255, c = threadIdx.x;
  const float* bp = bnp + i * 3072;
  double g0 = bp[0 + o],    be0 = bp[256 + o],  m0 = bp[512 + o],  v0 = bp[768 + o];
  double g1 = bp[1024 + o], be1 = bp[1280 + o], m1 = bp[1536 + o], v1 = bp[1792 + o];
  double g2 = bp[2048 + o], be2 = bp[2304 + o], m2 = bp[2560 + o], v2 = bp[2816 + o];
  double s0 = g0 / sqrt(v0 + 1e-5);
  double s1 = g1 / sqrt(v1 + 1e-5);
  double s2 = g2 / sqrt(v2 + 1e-5);
  size_t ro = (size_t)(i * 256 + o) * 256;
  float wa = (float)(s0 * (double)w1[ro + c]);
  float wb = (float)(s1 * s2 * (double)w2[ro + c]);
  u16 h, m, l;
  split3(wa, h, m, l); w1h[ro + c] = h; w1m[ro + c] = m; w1l[ro + c] = l;
  split3(wb, h, m, l); w2h[ro + c] = h; w2m[ro + c] = m; w2l[ro + c] = l;
  if (c == 0) {
    b0f[i * 256 + o] = (float)(be0 - m0 * s0);
    b2f[i * 256 + o] = (float)(s2 * (be1 - m1 * s1) + be2 - m2 * s2);
  }
}

// ---------------------------------------------------------------------------
// Head spike + transpose: x[b][c][p] fp32 -> xs[z][p][c] u8 {0,1} (exact)
// ---------------------------------------------------------------------------
__global__ __launch_bounds__(256) void head_spike(
    const float* __restrict__ x, u8* __restrict__ xs, int b0)
{
  __shared__ u8 tile[64][68];
  int z = blockIdx.z, c0 = blockIdx.y << 6, p0 = blockIdx.x << 6;
  int tid = threadIdx.x;
  const float* xb = x + ((size_t)(b0 + z) * CCH + c0) * HWP + p0;
#pragma unroll
  for (int j = 0; j < 16; ++j) {
    int idx = j * 256 + tid;
    int cl = idx >> 6, pl = idx & 63;
    tile[pl][cl] = (xb[(size_t)cl * HWP + pl] >= 2.0f) ? 1 : 0;
  }
  __syncthreads();
#pragma unroll
  for (int j = 0; j < 4; ++j) {
    int idx = j * 256 + tid;
    int row = idx >> 4, c4 = (idx & 15) << 2;
    *(uchar4*)(xs + ((size_t)z * HWP + p0 + row) * CCH + c0 + c4) =
        *(const uchar4*)&tile[row][c4];
  }
}

// ---------------------------------------------------------------------------
// u8 transpose: in[z][c][p] -> out[b0+z][p][c]   (s after attention)
// ---------------------------------------------------------------------------
__global__ __launch_bounds__(256) void transpose_s(
    const u8* __restrict__ in, u8* __restrict__ out, int b0)
{
  __shared__ u8 tile[64][68];
  int z = blockIdx.z, c0 = blockIdx.y << 6, p0 = blockIdx.x << 6;
  int tid = threadIdx.x;
#pragma unroll
  for (int j = 0; j < 4; ++j) {
    int idx = j * 256 + tid;
    int cl = idx >> 4, p4 = (idx & 15) << 2;
    uchar4 v = *(const uchar4*)(in + ((size_t)z * CCH + c0 + cl) * HWP + p0 + p4);
    tile[p4 + 0][cl] = v.x; tile[p4 + 1][cl] = v.y;
    tile[p4 + 2][cl] = v.z; tile[p4 + 3][cl] = v.w;
  }
  __syncthreads();
#pragma unroll
  for (int j = 0; j < 4; ++j) {
    int idx = j * 256 + tid;
    int row = idx >> 4, c4 = (idx & 15) << 2;
    *(uchar4*)(out + ((size_t)(b0 + z) * HWP + p0 + row) * CCH + c0 + c4) =
        *(const uchar4*)&tile[row][c4];
  }
}

// ---------------------------------------------------------------------------
// GEMM1 (round-4 proven): T1 = bias + act(binary u8) x W(3-split), 128x128
// tile, K=256.  W staged via swizzled global_load_lds.  Direct global W reads
// were tried (round 5) and REGRESSED (~25 us/dispatch: W loses all L2 reuse
// under the A stream; only the burst-DMA pattern keeps W L2-hot). Do not
// remove the staging.  launch_bounds(256,4): 4 blocks/CU, single round.
// ---------------------------------------------------------------------------
__global__ __launch_bounds__(256, 4) void gemm1(
    const u8* __restrict__ act, int b0in,
    const u16* __restrict__ WH, const u16* __restrict__ WM, const u16* __restrict__ WL,
    const float* __restrict__ bias, float* __restrict__ T1)
{
  __shared__ alignas(16) u16 As[128 * 40];
  __shared__ alignas(16) u16 LWH[4096];
  __shared__ alignas(16) u16 LWM[4096];
  __shared__ alignas(16) u16 LWL[4096];
  const int tid = threadIdx.x, wave = tid >> 6, lane = tid & 63;
  const int p0 = blockIdx.x * 128, o0 = blockIdx.y * 128, z = blockIdx.z;
  const int wm = (wave >> 1) * 64, wn = (wave & 1) * 64;
  const int lc = lane & 15, lr = lane >> 4;
  const u8* ab = act + ((size_t)(b0in + z) * HWP + p0) * CCH;
  const char* whb = (const char*)(WH + (size_t)o0 * 256);
  const char* wmb = (const char*)(WM + (size_t)o0 * 256);
  const char* wlb = (const char*)(WL + (size_t)o0 * 256);

  f32x4 acc[4][4];
#pragma unroll
  for (int i = 0; i < 4; ++i)
#pragma unroll
    for (int j = 0; j < 4; ++j) acc[i][j] = (f32x4){0.f, 0.f, 0.f, 0.f};

  const int srow = tid >> 1, shalf = tid & 1;

  for (int kc = 0; kc < 8; ++kc) {
    const int kof = kc * 64;
    __syncthreads();
    // kick W DMA (swizzled granules; same 64B line per 4 lanes)
#pragma unroll
    for (int t = 0; t < 2; ++t) {
      int li = t * 256 + tid;
      int row = li >> 2, ch = li & 3;
      int chp = (ch - row - (row >> 2)) & 3;
      size_t so = (size_t)row * 512 + kof + chp * 16;
      int base = (t * 256 + wave * 64) * 8;
      gl_lds16(whb + so, &LWH[base]);
      gl_lds16(wmb + so, &LWM[base]);
      gl_lds16(wlb + so, &LWL[base]);
    }
    // expand binary act into As (overlaps the DMA)
    uint4 u = *(const uint4*)(ab + (size_t)srow * CCH + kc * 32 + shalf * 16);
    u32 vv[4] = {u.x, u.y, u.z, u.w};
    u32 w[8];
#pragma unroll
    for (int q = 0; q < 4; ++q) {
      u32 v = vv[q];
      w[2 * q]     = ((v & 255u) ? 0x3F80u : 0u) | (((v >> 8) & 255u) ? 0x3F800000u : 0u);
      w[2 * q + 1] = (((v >> 16) & 255u) ? 0x3F80u : 0u) | (((v >> 24) & 255u) ? 0x3F800000u : 0u);
    }
    *(uint4*)&As[srow * 40 + shalf * 16]     = (uint4){w[0], w[1], w[2], w[3]};
    *(uint4*)&As[srow * 40 + shalf * 16 + 8] = (uint4){w[4], w[5], w[6], w[7]};
    __syncthreads();
    short8 af[4];
#pragma unroll
    for (int i = 0; i < 4; ++i)
      af[i] = *(const short8*)&As[(wm + i * 16 + lc) * 40 + lr * 8];
#pragma unroll
    for (int j = 0; j < 4; ++j) {
      int row = wn + j * 16 + lc;
      int o = row * 32 + ((lr + lc + (lc >> 2)) & 3) * 8;
      short8 bh = *(const short8*)&LWH[o];
      short8 bm = *(const short8*)&LWM[o];
      short8 bl = *(const short8*)&LWL[o];
#pragma unroll
      for (int i = 0; i < 4; ++i) {
        acc[i][j] = __builtin_amdgcn_mfma_f32_16x16x32_bf16(af[i], bl, acc[i][j], 0, 0, 0);
        acc[i][j] = __builtin_amdgcn_mfma_f32_16x16x32_bf16(af[i], bm, acc[i][j], 0, 0, 0);
        acc[i][j] = __builtin_amdgcn_mfma_f32_16x16x32_bf16(af[i], bh, acc[i][j], 0, 0, 0);
      }
    }
  }
  float* tb = T1 + ((size_t)z * HWP + p0) * CCH + o0;
#pragma unroll
  for (int j = 0; j < 4; ++j) {
    int n = wn + j * 16 + lc;
    float bn_ = bias[o0 + n];
#pragma unroll
    for (int i = 0; i < 4; ++i) {
      int m = wm + i * 16 + lr * 4;
#pragma unroll
      for (int r = 0; r < 4; ++r)
        tb[(size_t)(m + r) * CCH + n] = acc[i][j][r] + bn_;
    }
  }
}

// ---------------------------------------------------------------------------
// Depthwise 3x3 SAME: T1[z][p][c] fp32 -> 3-way split bf16 planes (pixel-major).
// ---------------------------------------------------------------------------
__global__ __launch_bounds__(256) void dw3(
    const float* __restrict__ t1, const float* __restrict__ dwk,
    u16* __restrict__ oh, u16* __restrict__ om, u16* __restrict__ ol)
{
  __shared__ float wl[2304];   // [c][9]
  int tid = threadIdx.x;
#pragma unroll
  for (int t = 0; t < 9; ++t) wl[t * 256 + tid] = dwk[t * 256 + tid];
  int c4 = (tid & 63) << 2;
  int pl = tid >> 6;
  int p = blockIdx.x * 4 + pl;
  int z = blockIdx.y;
  int y = p / 80, x = p - y * 80;
  __syncthreads();
  float a0 = 0.f, a1 = 0.f, a2 = 0.f, a3 = 0.f;
  const float* base = t1 + (size_t)z * HWP * CCH;
  const float* wc = &wl[c4 * 9];
#pragma unroll
  for (int dy = -1; dy <= 1; ++dy) {
    int yy = y + dy;
    bool vy = (unsigned)yy < 80u;
#pragma unroll
    for (int dx = -1; dx <= 1; ++dx) {
      int xx = x + dx;
      if (vy && (unsigned)xx < 80u) {
        float4 v = *(const float4*)(base + (size_t)(yy * 80 + xx) * CCH + c4);
        int t = (dy + 1) * 3 + (dx + 1);
        a0 += wc[t]      * v.x;
        a1 += wc[9 + t]  * v.y;
        a2 += wc[18 + t] * v.z;
        a3 += wc[27 + t] * v.w;
      }
    }
  }
  u16 h0, m0, l0, h1, m1, l1, h2, m2, l2, h3, m3, l3;
  split3(a0, h0, m0, l0);
  split3(a1, h1, m1, l1);
  split3(a2, h2, m2, l2);
  split3(a3, h3, m3, l3);
  u16x4 vh, vm, vlo;
  vh.x = h0; vh.y = h1; vh.z = h2; vh.w = h3;
  vm.x = m0; vm.y = m1; vm.z = m2; vm.w = m3;
  vlo.x = l0; vlo.y = l1; vlo.z = l2; vlo.w = l3;
  size_t addr = ((size_t)z * HWP + p) * CCH + c4;
  *(u16x4*)(oh + addr) = vh;
  *(u16x4*)(om + addr) = vm;
  *(u16x4*)(ol + addr) = vlo;
}

// ---------------------------------------------------------------------------
// GEMM2 v5: 512 threads, 128x256 FULL-o tile, K=256, 6 MFMA passes.
//  * BOTH operands staged via swizzled global_load_lds (rounds 3 & 5 proved
//    direct per-lane loads of either operand lose all L2 locality).
//  * 8 waves (2m x 4n); LDS = A 24 KB + W 48 KB = 72 KB -> 2 blocks/CU;
//    grid 50x8 = 400 <= capacity 512 -> single round (old form: 768 < 800,
//    two-round tail).  A staged once per (p0,z) instead of twice.
//  * Same stage/read swizzle algebra (chunk cancellation holds for
//    wn in {0,64,128,192}); MFMA order unchanged -> bitwise identical.
// MODE 0: fp32 channel-major out + bias; MODE 1: u8 spike; MODE 2: 3-split.
// ---------------------------------------------------------------------------
template <int MODE>
__global__ __launch_bounds__(512, 4) void gemm2s(
    const u16* __restrict__ AH, const u16* __restrict__ AM, const u16* __restrict__ AL,
    const u16* __restrict__ WH, const u16* __restrict__ WM, const u16* __restrict__ WL,
    const float* __restrict__ bias, int b0,
    float* __restrict__ outF, u8* __restrict__ outB,
    u16* __restrict__ outH, u16* __restrict__ outM, u16* __restrict__ outL)
{
  __shared__ alignas(16) u16 LAH[4096];
  __shared__ alignas(16) u16 LAM[4096];
  __shared__ alignas(16) u16 LAL[4096];
  __shared__ alignas(16) u16 LWH[8192];
  __shared__ alignas(16) u16 LWM[8192];
  __shared__ alignas(16) u16 LWL[8192];
  const int tid = threadIdx.x, wave = tid >> 6, lane = tid & 63;
  const int p0 = blockIdx.x * 128, z = blockIdx.y;
  const int wm = (wave >> 2) * 64, wn = (wave & 3) * 64;
  const int lc = lane & 15, lr = lane >> 4;
  const char* ahb = (const char*)(AH + ((size_t)z * HWP + p0) * 256);
  const char* amb = (const char*)(AM + ((size_t)z * HWP + p0) * 256);
  const char* alb = (const char*)(AL + ((size_t)z * HWP + p0) * 256);
  const char* whb = (const char*)WH;
  const char* wmb = (const char*)WM;
  const char* wlb = (const char*)WL;

  f32x4 acc[4][4];
#pragma unroll
  for (int i = 0; i < 4; ++i)
#pragma unroll
    for (int j = 0; j < 4; ++j) acc[i][j] = (f32x4){0.f, 0.f, 0.f, 0.f};

#pragma unroll 1
  for (int kc = 0; kc < 8; ++kc) {
    const int kof = kc * 64;
    // A: 128 rows, one DMA issue per plane (512 threads x 16B = 8 KB)
    {
      int li = tid;
      int row = li >> 2, ch = li & 3;
      int chp = (ch - row - (row >> 2)) & 3;
      size_t so = (size_t)row * 512 + kof + chp * 16;
      int base = wave * 512;                 // wave-uniform dst, lane x 16B
      gl_lds16(ahb + so, &LAH[base]);
      gl_lds16(amb + so, &LAM[base]);
      gl_lds16(alb + so, &LAL[base]);
    }
    // W: 256 rows, two DMA issues per plane
#pragma unroll
    for (int t = 0; t < 2; ++t) {
      int li = t * 512 + tid;
      int row = li >> 2, ch = li & 3;
      int chp = (ch - row - (row >> 2)) & 3;
      size_t so = (size_t)row * 512 + kof + chp * 16;
      int base = t * 4096 + wave * 512;      // wave-uniform dst
      gl_lds16(whb + so, &LWH[base]);
      gl_lds16(wmb + so, &LWM[base]);
      gl_lds16(wlb + so, &LWL[base]);
    }
    __syncthreads();
    short8 afH[4], afM[4], afL[4];
#pragma unroll
    for (int i = 0; i < 4; ++i) {
      int row = wm + i * 16 + lc;
      int o = row * 32 + ((lr + lc + (lc >> 2)) & 3) * 8;
      afH[i] = *(const short8*)&LAH[o];
      afM[i] = *(const short8*)&LAM[o];
      afL[i] = *(const short8*)&LAL[o];
    }
#pragma unroll
    for (int j = 0; j < 4; ++j) {
      int row = wn + j * 16 + lc;
      int o = row * 32 + ((lr + lc + (lc >> 2)) & 3) * 8;
      short8 bh = *(const short8*)&LWH[o];
      short8 bm = *(const short8*)&LWM[o];
      short8 bl = *(const short8*)&LWL[o];
#pragma unroll
      for (int i = 0; i < 4; ++i) {
        acc[i][j] = __builtin_amdgcn_mfma_f32_16x16x32_bf16(afM[i], bm, acc[i][j], 0, 0, 0);
        acc[i][j] = __builtin_amdgcn_mfma_f32_16x16x32_bf16(afL[i], bh, acc[i][j], 0, 0, 0);
        acc[i][j] = __builtin_amdgcn_mfma_f32_16x16x32_bf16(afH[i], bl, acc[i][j], 0, 0, 0);
        acc[i][j] = __builtin_amdgcn_mfma_f32_16x16x32_bf16(afM[i], bh, acc[i][j], 0, 0, 0);
        acc[i][j] = __builtin_amdgcn_mfma_f32_16x16x32_bf16(afH[i], bm, acc[i][j], 0, 0, 0);
        acc[i][j] = __builtin_amdgcn_mfma_f32_16x16x32_bf16(afH[i], bh, acc[i][j], 0, 0, 0);
      }
    }
    __syncthreads();   // all waves done reading LDS before next-step DMA overwrites
  }
  // Epilogue: channel-major, m = pixel, n = out-channel (full 0..255).
#pragma unroll
  for (int j = 0; j < 4; ++j) {
    int n = wn + j * 16 + lc;
    float bn_ = bias[n];
    size_t rowb = ((size_t)(b0 + z) * CCH + n) * HWP + p0;
#pragma unroll
    for (int i = 0; i < 4; ++i) {
      int m = wm + i * 16 + lr * 4;
      if (MODE == 0) {
        float4 o;
        o.x = acc[i][j][0] + bn_; o.y = acc[i][j][1] + bn_;
        o.z = acc[i][j][2] + bn_; o.w = acc[i][j][3] + bn_;
        *(float4*)(outF + rowb + m) = o;
      } else if (MODE == 1) {
        uchar4 o;
        o.x = (acc[i][j][0] + bn_ >= 2.0f) ? 1 : 0;
        o.y = (acc[i][j][1] + bn_ >= 2.0f) ? 1 : 0;
        o.z = (acc[i][j][2] + bn_ >= 2.0f) ? 1 : 0;
        o.w = (acc[i][j][3] + bn_ >= 2.0f) ? 1 : 0;
        *(uchar4*)(outB + rowb + m) = o;
      } else {
        u16x4 vh, vm2, vl2;
#pragma unroll
        for (int r = 0; r < 4; ++r) {
          u16 hh, mm, ll;
          split3(acc[i][j][r] + bn_, hh, mm, ll);
          vh[r] = hh; vm2[r] = mm; vl2[r] = ll;
        }
        *(u16x4*)(outH + rowb + m) = vh;
        *(u16x4*)(outM + rowb + m) = vm2;
        *(u16x4*)(outL + rowb + m) = vl2;
      }
    }
  }
}

// ---------------------------------------------------------------------------
// Attention per (z,c): Q and K arrive PRE-SPLIT (3 bf16 planes each, from
// gemm2s MODE 2) -- no split3 in the staging path at all.
// 320 threads: wave = m-tile. LDS row stride 104 u16 (2-way b128 reads).
// ---------------------------------------------------------------------------
__global__ __launch_bounds__(320) void attn_k(
    const u16* __restrict__ qh_g, const u16* __restrict__ qm_g, const u16* __restrict__ ql_g,
    const u16* __restrict__ kh_g, const u16* __restrict__ km_g, const u16* __restrict__ kl_g,
    const u8* __restrict__ vv, u8* __restrict__ s)
{
  __shared__ alignas(16) u16 L[24960];   // K 3-split [h'][w]; overlaid by S 3-split [h][h']
  __shared__ alignas(16) u8  VT[8320];   // V^T [u][h'] stride 104
  const int tid = threadIdx.x, wave = tid >> 6, lane = tid & 63;
  const int lc = lane & 15, lr = lane >> 4;
  const size_t off = (size_t)blockIdx.x * HWP;
  u16* KH = L; u16* KM = L + 8320; u16* KL = L + 16640;

  // Hoist Q fragments: row h = wave*16+lc, k-cols w0..w0+7.
  short8 qfr[3][3];  // [kc][h/m/l]
  const int hrow = wave * 16 + lc;
#pragma unroll
  for (int kc = 0; kc < 3; ++kc) {
    int w0 = kc * 32 + lr * 8;
    if (w0 < 80) {
      size_t qo = off + (size_t)hrow * 80 + w0;
      qfr[kc][0] = *(const short8*)(qh_g + qo);
      qfr[kc][1] = *(const short8*)(qm_g + qo);
      qfr[kc][2] = *(const short8*)(ql_g + qo);
    } else {
      qfr[kc][0] = (short8){0, 0, 0, 0, 0, 0, 0, 0};
      qfr[kc][1] = qfr[kc][0];
      qfr[kc][2] = qfr[kc][0];
    }
  }

  // Stage K 3-split planes: 12 granules/row (10 data + 2 zero pad), 80 rows.
#pragma unroll
  for (int t = 0; t < 3; ++t) {
    int g = t * 320 + tid;            // 0..959
    int h = g / 12, wc = g - h * 12;
    int dst = h * 104 + wc * 8;
    if (wc < 10) {
      size_t so = off + (size_t)h * 80 + wc * 8;
      *(short8*)&KH[dst] = *(const short8*)(kh_g + so);
      *(short8*)&KM[dst] = *(const short8*)(km_g + so);
      *(short8*)&KL[dst] = *(const short8*)(kl_g + so);
    } else {
      short8 z8 = (short8){0, 0, 0, 0, 0, 0, 0, 0};
      *(short8*)&KH[dst] = z8; *(short8*)&KM[dst] = z8; *(short8*)&KL[dst] = z8;
    }
  }
  // VT pads (cols 80..95): 80 rows x 4 dwords, exactly 320 threads.
  {
    int row = tid >> 2, qq = tid & 3;
    *(u32*)&VT[row * 104 + 80 + qq * 4] = 0;
  }
  // VT transpose stage: uchar4 reads, byte scatter.
#pragma unroll
  for (int t = 0; t < 5; ++t) {
    int q = t * 320 + tid;            // 0..1599 quads
    int h = q / 20, w4 = (q - h * 20) * 4;
    uchar4 v4 = *(const uchar4*)(vv + off + (size_t)h * 80 + w4);
    VT[(w4 + 0) * 104 + h] = v4.x;
    VT[(w4 + 1) * 104 + h] = v4.y;
    VT[(w4 + 2) * 104 + h] = v4.z;
    VT[(w4 + 3) * 104 + h] = v4.w;
  }
  __syncthreads();

  // Stage 1: S = Q K^T.  m-rows h = wave*16+lc, k = w (pad 96), n = h'.
  f32x4 accS[5];
#pragma unroll
  for (int n = 0; n < 5; ++n) accS[n] = (f32x4){0.f, 0.f, 0.f, 0.f};
  for (int kc = 0; kc < 3; ++kc) {
#pragma unroll
    for (int n = 0; n < 5; ++n) {
      int bo = (n * 16 + lc) * 104 + kc * 32 + lr * 8;
      short8 kh_ = *(const short8*)&KH[bo];
      short8 km_ = *(const short8*)&KM[bo];
      short8 kl_ = *(const short8*)&KL[bo];
      __builtin_amdgcn_s_setprio(1);
      accS[n] = __builtin_amdgcn_mfma_f32_16x16x32_bf16(qfr[kc][0], kl_, accS[n], 0, 0, 0);
      accS[n] = __builtin_amdgcn_mfma_f32_16x16x32_bf16(qfr[kc][2], kh_, accS[n], 0, 0, 0);
      accS[n] = __builtin_amdgcn_mfma_f32_16x16x32_bf16(qfr[kc][1], km_, accS[n], 0, 0, 0);
      accS[n] = __builtin_amdgcn_mfma_f32_16x16x32_bf16(qfr[kc][1], kh_, accS[n], 0, 0, 0);
      accS[n] = __builtin_amdgcn_mfma_f32_16x16x32_bf16(qfr[kc][0], km_, accS[n], 0, 0, 0);
      accS[n] = __builtin_amdgcn_mfma_f32_16x16x32_bf16(qfr[kc][0], kh_, accS[n], 0, 0, 0);
      __builtin_amdgcn_s_setprio(0);
    }
  }
  __syncthreads();   // all K reads done; L becomes S (pads stay zero)
#pragma unroll
  for (int n = 0; n < 5; ++n) {
#pragma unroll
    for (int r = 0; r < 4; ++r) {
      u16 hh, mm, ll; split3(accS[n][r], hh, mm, ll);
      int o = (wave * 16 + lr * 4 + r) * 104 + n * 16 + lc;
      KH[o] = hh; KM[o] = mm; KL[o] = ll;
    }
  }
  __syncthreads();
  // Stage 2: attn = S V ; spike at raw >= 8  (attn*0.125 >= 1)
  f32x4 accA[5];
#pragma unroll
  for (int n = 0; n < 5; ++n) accA[n] = (f32x4){0.f, 0.f, 0.f, 0.f};
  for (int kc = 0; kc < 3; ++kc) {
    int ao = (wave * 16 + lc) * 104 + kc * 32 + lr * 8;
    short8 sh_ = *(const short8*)&KH[ao];
    short8 sm_ = *(const short8*)&KM[ao];
    short8 sl_ = *(const short8*)&KL[ao];
#pragma unroll
    for (int n = 0; n < 5; ++n) {
      const u8* vp = &VT[(n * 16 + lc) * 104 + kc * 32 + lr * 8];
      u32 b0 = *(const u32*)vp;
      u32 b1 = *(const u32*)(vp + 4);
      u32 e0 = ((b0 & 255u) ? 0x3F80u : 0u) | (((b0 >> 8) & 255u) ? 0x3F800000u : 0u);
      u32 e1 = (((b0 >> 16) & 255u) ? 0x3F80u : 0u) | (((b0 >> 24) & 255u) ? 0x3F800000u : 0u);
      u32 e2 = ((b1 & 255u) ? 0x3F80u : 0u) | (((b1 >> 8) & 255u) ? 0x3F800000u : 0u);
      u32 e3 = (((b1 >> 16) & 255u) ? 0x3F80u : 0u) | (((b1 >> 24) & 255u) ? 0x3F800000u : 0u);
      u32 vbw[4] = {e0, e1, e2, e3};
      short8 vb = *(const short8*)vbw;
      __builtin_amdgcn_s_setprio(1);
      accA[n] = __builtin_amdgcn_mfma_f32_16x16x32_bf16(sl_, vb, accA[n], 0, 0, 0);
      accA[n] = __builtin_amdgcn_mfma_f32_16x16x32_bf16(sm_, vb, accA[n], 0, 0, 0);
      accA[n] = __builtin_amdgcn_mfma_f32_16x16x32_bf16(sh_, vb, accA[n], 0, 0, 0);
      __builtin_amdgcn_s_setprio(0);
    }
  }
#pragma unroll
  for (int n = 0; n < 5; ++n)
#pragma unroll
    for (int r = 0; r < 4; ++r)
      s[off + (size_t)(wave * 16 + lr * 4 + r) * 80 + n * 16 + lc] =
          (accA[n][r] >= 8.0f) ? 1 : 0;
}

// ---------------------------------------------------------------------------
extern "C" void kernel_launch(void* const* d_in, const int* in_sizes, int n_in,
                              void* d_out, int out_size, void* d_ws, size_t ws_size,
                              hipStream_t stream)
{
  const float* x   = (const float*)d_in[0];
  const float* w1  = (const float*)d_in[1];
  const float* dwk = (const float*)d_in[2];
  const float* w2  = (const float*)d_in[3];
  const float* bnp = (const float*)d_in[4];
  float* out = (float*)d_out;
  char* ws = (char*)d_ws;

  // Workspace layout (~292 MB total, unchanged size).
  u16* W1H = (u16*)(ws + 0);
  u16* W1M = (u16*)(ws + 524288);
  u16* W1L = (u16*)(ws + 1048576);
  u16* W2H = (u16*)(ws + 1572864);
  u16* W2M = (u16*)(ws + 2097152);
  u16* W2L = (u16*)(ws + 2621440);
  float* B0F = (float*)(ws + 3145728);
  float* B2F = (float*)(ws + 3149824);
  u8*    SPM = (u8*)(ws + 3153920);          // s pixel-major, full 16 batches
  u8*    XS  = (u8*)(ws + 29368320);         // xs, half-batch chunk
  float* T1  = (float*)(ws + 42475520);      // fp32 branch tmp, half chunk
  u16*   KH_ = (u16*)(ws + 42475520);        // overlays T1 (T1 dead at write time)
  u16*   KM_ = (u16*)(ws + 68689920);
  u16*   QH_ = (u16*)(ws + 94904320);        // old QF region start
  u16*   QM_ = (u16*)(ws + 121118720);
  u16*   QL_ = (u16*)(ws + 147333120);
  u16*   KL_ = (u16*)(ws + 173547520);       // old KF region tail
  u8*    V   = (u8*)(ws + 199761920);        // v binary CM (s_cm in-place)
  u16*   D2H = (u16*)(ws + 212869120);       // dw split hi, pixel-major
  u16*   D2M = (u16*)(ws + 239083520);
  u16*   D2L = (u16*)(ws + 265297920);       // ends 291512320

  dim3 gb(256);
  fold_weights<<<dim3(1024), gb, 0, stream>>>(w1, w2, bnp,
      W1H, W1M, W1L, W2H, W2M, W2L, B0F, B2F);

  for (int c = 0; c < 2; ++c) {
    int b0 = c * 8;
    dim3 gh(100, 4, 8), gg(50, 2, 8), gg2(50, 8), gd(1600, 8);
    head_spike<<<gh, gb, 0, stream>>>(x, XS, b0);
    // v branch (binary spike epilogue) -- first, so T1 is free for K planes later
    gemm1<<<gg, gb, 0, stream>>>(XS, 0, W1H + 2 * 65536, W1M + 2 * 65536, W1L + 2 * 65536,
                                 B0F + 512, T1);
    dw3<<<gd, gb, 0, stream>>>(T1, dwk + 2 * 2304, D2H, D2M, D2L);
    gemm2s<1><<<gg2, dim3(512), 0, stream>>>(D2H, D2M, D2L,
                                     W2H + 2 * 65536, W2M + 2 * 65536, W2L + 2 * 65536,
                                     B2F + 512, 0, nullptr, V, nullptr, nullptr, nullptr);
    // q branch -> pre-split planes
    gemm1<<<gg, gb, 0, stream>>>(XS, 0, W1H + 0 * 65536, W1M + 0 * 65536, W1L + 0 * 65536,
                                 B0F + 0, T1);
    dw3<<<gd, gb, 0, stream>>>(T1, dwk + 0 * 2304, D2H, D2M, D2L);
    gemm2s<2><<<gg2, dim3(512), 0, stream>>>(D2H, D2M, D2L,
                                     W2H + 0 * 65536, W2M + 0 * 65536, W2L + 0 * 65536,
                                     B2F + 0, 0, nullptr, nullptr, QH_, QM_, QL_);
    // k branch -> pre-split planes (KH_/KM_ overlay T1, which is dead by then)
    gemm1<<<gg, gb, 0, stream>>>(XS, 0, W1H + 1 * 65536, W1M + 1 * 65536, W1L + 1 * 65536,
                                 B0F + 256, T1);
    dw3<<<gd, gb, 0, stream>>>(T1, dwk + 1 * 2304, D2H, D2M, D2L);
    gemm2s<2><<<gg2, dim3(512), 0, stream>>>(D2H, D2M, D2L,
                                     W2H + 1 * 65536, W2M + 1 * 65536, W2L + 1 * 65536,
                                     B2F + 256, 0, nullptr, nullptr, KH_, KM_, KL_);
    // attention -> s channel-major (in-place over V), then to pixel-major SPM
    attn_k<<<dim3(2048), dim3(320), 0, stream>>>(QH_, QM_, QL_, KH_, KM_, KL_, V, V);
    transpose_s<<<gh, gb, 0, stream>>>(V, SPM, b0);
  }
  // proj branch -> fp32 d_out (channel-major), chunked to fit T1
  for (int c = 0; c < 2; ++c) {
    int b0 = c * 8;
    dim3 gg(50, 2, 8), gg2(50, 8), gd(1600, 8);
    gemm1<<<gg, gb, 0, stream>>>(SPM, b0, W1H + 3 * 65536, W1M + 3 * 65536, W1L + 3 * 65536,
                                 B0F + 768, T1);
    dw3<<<gd, gb, 0, stream>>>(T1, dwk + 3 * 2304, D2H, D2M, D2L);
    gemm2s<0><<<gg2, dim3(512), 0, stream>>>(D2H, D2M, D2L,
                                     W2H + 3 * 65536, W2M + 3 * 65536, W2L + 3 * 65536,
                                     B2F + 768, b0, out, nullptr, nullptr, nullptr, nullptr);
  }
}

// Round 7
// 1342.543 us; speedup vs baseline: 1.5587x; 1.1921x over previous
//
#include <hip/hip_runtime.h>
#include <hip/hip_bf16.h>
#include <cstdint>
#include <cstddef>
#include <cmath>

typedef unsigned short u16;
typedef unsigned char  u8;
typedef unsigned int   u32;
typedef __attribute__((ext_vector_type(8))) short short8;   // 8 bf16 MFMA frag
typedef __attribute__((ext_vector_type(4))) float f32x4;    // MFMA accumulator
typedef __attribute__((ext_vector_type(4))) u16 u16x4;

#define CCH 256
#define HWP 6400   // 80*80

__device__ __forceinline__ u16 f2bf(float f) {
  u32 u = __float_as_uint(f);
  u = (u + 0x7FFFu + ((u >> 16) & 1u)) >> 16;   // RNE
  return (u16)u;
}
__device__ __forceinline__ float bf2f(u16 h) { return __uint_as_float(((u32)h) << 16); }
__device__ __forceinline__ void split3(float v, u16& h, u16& m, u16& l) {
  h = f2bf(v); float r = v - bf2f(h);
  m = f2bf(r); l = f2bf(r - bf2f(m));
}
__device__ __forceinline__ void gl_lds16(const void* g, void* l) {
  __builtin_amdgcn_global_load_lds((const __attribute__((address_space(1))) unsigned int*)g,
                                   (__attribute__((address_space(3))) unsigned int*)l,
                                   16, 0, 0);
}

// ---------------------------------------------------------------------------
// Fold BN into conv weights; emit 3-way split bf16 weights + fp32 biases.
// ---------------------------------------------------------------------------
__global__ __launch_bounds__(256) void fold_weights(
    const float* __restrict__ w1, const float* __restrict__ w2,
    const float* __restrict__ bnp,
    u16* __restrict__ w1h, u16* __restrict__ w1m, u16* __restrict__ w1l,
    u16* __restrict__ w2h, u16* __restrict__ w2m, u16* __restrict__ w2l,
    float* __restrict__ b0f, float* __restrict__ b2f)
{
  int i = blockIdx.x >> 8, o = blockIdx.x & 255, c = threadIdx.x;
  const float* bp = bnp + i * 3072;
  double g0 = bp[0 + o],    be0 = bp[256 + o],  m0 = bp[512 + o],  v0 = bp[768 + o];
  double g1 = bp[1024 + o], be1 = bp[1280 + o], m1 = bp[1536 + o], v1 = bp[1792 + o];
  double g2 = bp[2048 + o], be2 = bp[2304 + o], m2 = bp[2560 + o], v2 = bp[2816 + o];
  double s0 = g0 / sqrt(v0 + 1e-5);
  double s1 = g1 / sqrt(v1 + 1e-5);
  double s2 = g2 / sqrt(v2 + 1e-5);
  size_t ro = (size_t)(i * 256 + o) * 256;
  float wa = (float)(s0 * (double)w1[ro + c]);
  float wb = (float)(s1 * s2 * (double)w2[ro + c]);
  u16 h, m, l;
  split3(wa, h, m, l); w1h[ro + c] = h; w1m[ro + c] = m; w1l[ro + c] = l;
  split3(wb, h, m, l); w2h[ro + c] = h; w2m[ro + c] = m; w2l[ro + c] = l;
  if (c == 0) {
    b0f[i * 256 + o] = (float)(be0 - m0 * s0);
    b2f[i * 256 + o] = (float)(s2 * (be1 - m1 * s1) + be2 - m2 * s2);
  }
}

// ---------------------------------------------------------------------------
// Head spike + transpose: x[b][c][p] fp32 -> xs[z][p][c] u8 {0,1} (exact)
// ---------------------------------------------------------------------------
__global__ __launch_bounds__(256) void head_spike(
    const float* __restrict__ x, u8* __restrict__ xs, int b0)
{
  __shared__ u8 tile[64][68];
  int z = blockIdx.z, c0 = blockIdx.y << 6, p0 = blockIdx.x << 6;
  int tid = threadIdx.x;
  const float* xb = x + ((size_t)(b0 + z) * CCH + c0) * HWP + p0;
#pragma unroll
  for (int j = 0; j < 16; ++j) {
    int idx = j * 256 + tid;
    int cl = idx >> 6, pl = idx & 63;
    tile[pl][cl] = (xb[(size_t)cl * HWP + pl] >= 2.0f) ? 1 : 0;
  }
  __syncthreads();
#pragma unroll
  for (int j = 0; j < 4; ++j) {
    int idx = j * 256 + tid;
    int row = idx >> 4, c4 = (idx & 15) << 2;
    *(uchar4*)(xs + ((size_t)z * HWP + p0 + row) * CCH + c0 + c4) =
        *(const uchar4*)&tile[row][c4];
  }
}

// ---------------------------------------------------------------------------
// u8 transpose: in[z][c][p] -> out[b0+z][p][c]   (s after attention)
// ---------------------------------------------------------------------------
__global__ __launch_bounds__(256) void transpose_s(
    const u8* __restrict__ in, u8* __restrict__ out, int b0)
{
  __shared__ u8 tile[64][68];
  int z = blockIdx.z, c0 = blockIdx.y << 6, p0 = blockIdx.x << 6;
  int tid = threadIdx.x;
#pragma unroll
  for (int j = 0; j < 4; ++j) {
    int idx = j * 256 + tid;
    int cl = idx >> 4, p4 = (idx & 15) << 2;
    uchar4 v = *(const uchar4*)(in + ((size_t)z * CCH + c0 + cl) * HWP + p0 + p4);
    tile[p4 + 0][cl] = v.x; tile[p4 + 1][cl] = v.y;
    tile[p4 + 2][cl] = v.z; tile[p4 + 3][cl] = v.w;
  }
  __syncthreads();
#pragma unroll
  for (int j = 0; j < 4; ++j) {
    int idx = j * 256 + tid;
    int row = idx >> 4, c4 = (idx & 15) << 2;
    *(uchar4*)(out + ((size_t)(b0 + z) * HWP + p0 + row) * CCH + c0 + c4) =
        *(const uchar4*)&tile[row][c4];
  }
}

// ---------------------------------------------------------------------------
// GEMM1 (round-4 proven): T1 = bias + act(binary u8) x W(3-split), 128x128
// tile, K=256.  W staged via swizzled global_load_lds.  Direct global reads
// of either operand REGRESS (rounds 3 & 5: L2 thrash). launch_bounds(256,4).
// ---------------------------------------------------------------------------
__global__ __launch_bounds__(256, 4) void gemm1(
    const u8* __restrict__ act, int b0in,
    const u16* __restrict__ WH, const u16* __restrict__ WM, const u16* __restrict__ WL,
    const float* __restrict__ bias, float* __restrict__ T1)
{
  __shared__ alignas(16) u16 As[128 * 40];
  __shared__ alignas(16) u16 LWH[4096];
  __shared__ alignas(16) u16 LWM[4096];
  __shared__ alignas(16) u16 LWL[4096];
  const int tid = threadIdx.x, wave = tid >> 6, lane = tid & 63;
  const int p0 = blockIdx.x * 128, o0 = blockIdx.y * 128, z = blockIdx.z;
  const int wm = (wave >> 1) * 64, wn = (wave & 1) * 64;
  const int lc = lane & 15, lr = lane >> 4;
  const u8* ab = act + ((size_t)(b0in + z) * HWP + p0) * CCH;
  const char* whb = (const char*)(WH + (size_t)o0 * 256);
  const char* wmb = (const char*)(WM + (size_t)o0 * 256);
  const char* wlb = (const char*)(WL + (size_t)o0 * 256);

  f32x4 acc[4][4];
#pragma unroll
  for (int i = 0; i < 4; ++i)
#pragma unroll
    for (int j = 0; j < 4; ++j) acc[i][j] = (f32x4){0.f, 0.f, 0.f, 0.f};

  const int srow = tid >> 1, shalf = tid & 1;

  for (int kc = 0; kc < 8; ++kc) {
    const int kof = kc * 64;
    __syncthreads();
    // kick W DMA (swizzled granules; same 64B line per 4 lanes)
#pragma unroll
    for (int t = 0; t < 2; ++t) {
      int li = t * 256 + tid;
      int row = li >> 2, ch = li & 3;
      int chp = (ch - row - (row >> 2)) & 3;
      size_t so = (size_t)row * 512 + kof + chp * 16;
      int base = (t * 256 + wave * 64) * 8;
      gl_lds16(whb + so, &LWH[base]);
      gl_lds16(wmb + so, &LWM[base]);
      gl_lds16(wlb + so, &LWL[base]);
    }
    // expand binary act into As (overlaps the DMA)
    uint4 u = *(const uint4*)(ab + (size_t)srow * CCH + kc * 32 + shalf * 16);
    u32 vv[4] = {u.x, u.y, u.z, u.w};
    u32 w[8];
#pragma unroll
    for (int q = 0; q < 4; ++q) {
      u32 v = vv[q];
      w[2 * q]     = ((v & 255u) ? 0x3F80u : 0u) | (((v >> 8) & 255u) ? 0x3F800000u : 0u);
      w[2 * q + 1] = (((v >> 16) & 255u) ? 0x3F80u : 0u) | (((v >> 24) & 255u) ? 0x3F800000u : 0u);
    }
    *(uint4*)&As[srow * 40 + shalf * 16]     = (uint4){w[0], w[1], w[2], w[3]};
    *(uint4*)&As[srow * 40 + shalf * 16 + 8] = (uint4){w[4], w[5], w[6], w[7]};
    __syncthreads();
    short8 af[4];
#pragma unroll
    for (int i = 0; i < 4; ++i)
      af[i] = *(const short8*)&As[(wm + i * 16 + lc) * 40 + lr * 8];
#pragma unroll
    for (int j = 0; j < 4; ++j) {
      int row = wn + j * 16 + lc;
      int o = row * 32 + ((lr + lc + (lc >> 2)) & 3) * 8;
      short8 bh = *(const short8*)&LWH[o];
      short8 bm = *(const short8*)&LWM[o];
      short8 bl = *(const short8*)&LWL[o];
#pragma unroll
      for (int i = 0; i < 4; ++i) {
        acc[i][j] = __builtin_amdgcn_mfma_f32_16x16x32_bf16(af[i], bl, acc[i][j], 0, 0, 0);
        acc[i][j] = __builtin_amdgcn_mfma_f32_16x16x32_bf16(af[i], bm, acc[i][j], 0, 0, 0);
        acc[i][j] = __builtin_amdgcn_mfma_f32_16x16x32_bf16(af[i], bh, acc[i][j], 0, 0, 0);
      }
    }
  }
  float* tb = T1 + ((size_t)z * HWP + p0) * CCH + o0;
#pragma unroll
  for (int j = 0; j < 4; ++j) {
    int n = wn + j * 16 + lc;
    float bn_ = bias[o0 + n];
#pragma unroll
    for (int i = 0; i < 4; ++i) {
      int m = wm + i * 16 + lr * 4;
#pragma unroll
      for (int r = 0; r < 4; ++r)
        tb[(size_t)(m + r) * CCH + n] = acc[i][j][r] + bn_;
    }
  }
}

// ---------------------------------------------------------------------------
// Depthwise 3x3 SAME, v2: 2D-tiled.  Block = 8x8 pixel patch x 64 channels;
// 10x10 halo window staged in LDS (zero-padded at image border), 9 taps read
// from LDS.  Read amplification 9x -> 1.56x.  Tap order and fma contraction
// identical to v1; OOB taps contribute w*0 (+0 add, bitwise-neutral).
// Grid: (100 tiles, 4 chan-groups, 8 z).  LDS ~29.5 KB -> 5 blocks/CU.
// ---------------------------------------------------------------------------
__global__ __launch_bounds__(256) void dw3(
    const float* __restrict__ t1, const float* __restrict__ dwk,
    u16* __restrict__ oh, u16* __restrict__ om, u16* __restrict__ ol)
{
  __shared__ float lds[100 * 68];   // [slot sy*10+sx][ch 0..63], stride 68 pads banks
  __shared__ float wl[576];         // [c_local][9]
  const int tid = threadIdx.x;
  const int T = blockIdx.x, cg = blockIdx.y, z = blockIdx.z;
  const int ty0 = (T / 10) * 8, tx0 = (T % 10) * 8;
  const float* base = t1 + (size_t)z * HWP * CCH + cg * 64;

  // weights for this channel group: dwk[(cg*64 + c)][9]
#pragma unroll
  for (int t = 0; t < 3; ++t) {
    int i = t * 256 + tid;
    if (i < 576) wl[i] = dwk[cg * 576 + i];
  }
  // stage 10x10 window x 64 ch (1600 float4 quads)
#pragma unroll
  for (int t = 0; t < 7; ++t) {
    int idx = t * 256 + tid;
    if (idx < 1600) {
      int pxslot = idx >> 4;
      int c4i = (idx & 15) << 2;
      int sy = pxslot / 10, sx = pxslot - sy * 10;
      int wy = ty0 + sy - 1, wx = tx0 + sx - 1;
      float4 v = (float4){0.f, 0.f, 0.f, 0.f};
      if ((unsigned)wy < 80u && (unsigned)wx < 80u)
        v = *(const float4*)(base + (size_t)(wy * 80 + wx) * CCH + c4i);
      *(float4*)&lds[pxslot * 68 + c4i] = v;
    }
  }
  __syncthreads();

  const int cc = (tid & 15) << 2;        // channel-local base 0..60
  const float* wc = &wl[cc * 9];
#pragma unroll
  for (int i = 0; i < 4; ++i) {
    int p_local = (tid >> 4) + i * 16;   // 0..63
    int ly = p_local >> 3, lx = p_local & 7;
    float a0 = 0.f, a1 = 0.f, a2 = 0.f, a3 = 0.f;
#pragma unroll
    for (int dy = -1; dy <= 1; ++dy) {
#pragma unroll
      for (int dx = -1; dx <= 1; ++dx) {
        int slot = (ly + 1 + dy) * 10 + (lx + 1 + dx);
        float4 v = *(const float4*)&lds[slot * 68 + cc];
        int t = (dy + 1) * 3 + (dx + 1);
        a0 += wc[t]      * v.x;
        a1 += wc[9 + t]  * v.y;
        a2 += wc[18 + t] * v.z;
        a3 += wc[27 + t] * v.w;
      }
    }
    u16 h0, m0, l0, h1, m1, l1, h2, m2, l2, h3, m3, l3;
    split3(a0, h0, m0, l0);
    split3(a1, h1, m1, l1);
    split3(a2, h2, m2, l2);
    split3(a3, h3, m3, l3);
    u16x4 vh, vm, vlo;
    vh.x = h0; vh.y = h1; vh.z = h2; vh.w = h3;
    vm.x = m0; vm.y = m1; vm.z = m2; vm.w = m3;
    vlo.x = l0; vlo.y = l1; vlo.z = l2; vlo.w = l3;
    int p = (ty0 + ly) * 80 + tx0 + lx;
    size_t addr = ((size_t)z * HWP + p) * CCH + cg * 64 + cc;
    *(u16x4*)(oh + addr) = vh;
    *(u16x4*)(om + addr) = vm;
    *(u16x4*)(ol + addr) = vlo;
  }
}

// ---------------------------------------------------------------------------
// GEMM2 (round-2/4 proven form): out = bias + dwact(3-split) x W2(3-split),
// 6 MFMA passes, K=256.  BOTH operands staged via swizzled global_load_lds.
// Direct per-lane loads of A (round 3) or W (round 5) quadruple/double HBM
// traffic via L2 line thrash; the 512-thread full-o tile (round 6) loses to
// grid imbalance.  This 128x128 / 800-block / 48KB form is the local optimum.
// MODE 0: fp32 CM out + bias; MODE 1: u8 spike; MODE 2: 3-split planes.
// ---------------------------------------------------------------------------
template <int MODE>
__global__ __launch_bounds__(256) void gemm2s(
    const u16* __restrict__ AH, const u16* __restrict__ AM, const u16* __restrict__ AL,
    const u16* __restrict__ WH, const u16* __restrict__ WM, const u16* __restrict__ WL,
    const float* __restrict__ bias, int b0,
    float* __restrict__ outF, u8* __restrict__ outB,
    u16* __restrict__ outH, u16* __restrict__ outM, u16* __restrict__ outL)
{
  __shared__ alignas(16) u16 LAH[4096];
  __shared__ alignas(16) u16 LAM[4096];
  __shared__ alignas(16) u16 LAL[4096];
  __shared__ alignas(16) u16 LWH[4096];
  __shared__ alignas(16) u16 LWM[4096];
  __shared__ alignas(16) u16 LWL[4096];
  const int tid = threadIdx.x, wave = tid >> 6, lane = tid & 63;
  const int p0 = blockIdx.x * 128, o0 = blockIdx.y * 128, z = blockIdx.z;
  const int wm = (wave >> 1) * 64, wn = (wave & 1) * 64;
  const int lc = lane & 15, lr = lane >> 4;
  const char* ahb = (const char*)(AH + ((size_t)z * HWP + p0) * 256);
  const char* amb = (const char*)(AM + ((size_t)z * HWP + p0) * 256);
  const char* alb = (const char*)(AL + ((size_t)z * HWP + p0) * 256);
  const char* whb = (const char*)(WH + (size_t)o0 * 256);
  const char* wmb = (const char*)(WM + (size_t)o0 * 256);
  const char* wlb = (const char*)(WL + (size_t)o0 * 256);

  f32x4 acc[4][4];
#pragma unroll
  for (int i = 0; i < 4; ++i)
#pragma unroll
    for (int j = 0; j < 4; ++j) acc[i][j] = (f32x4){0.f, 0.f, 0.f, 0.f};

  for (int kc = 0; kc < 8; ++kc) {
    const int kof = kc * 64;
#pragma unroll
    for (int t = 0; t < 2; ++t) {
      int li = t * 256 + tid;
      int row = li >> 2, ch = li & 3;
      int chp = (ch - row - (row >> 2)) & 3;   // swizzled source granule
      size_t so = (size_t)row * 512 + kof + chp * 16;
      int base = (t * 256 + wave * 64) * 8;
      gl_lds16(ahb + so, &LAH[base]);
      gl_lds16(amb + so, &LAM[base]);
      gl_lds16(alb + so, &LAL[base]);
      gl_lds16(whb + so, &LWH[base]);
      gl_lds16(wmb + so, &LWM[base]);
      gl_lds16(wlb + so, &LWL[base]);
    }
    __syncthreads();
    short8 afH[4], afM[4], afL[4];
#pragma unroll
    for (int i = 0; i < 4; ++i) {
      int row = wm + i * 16 + lc;
      int o = row * 32 + ((lr + lc + (lc >> 2)) & 3) * 8;
      afH[i] = *(const short8*)&LAH[o];
      afM[i] = *(const short8*)&LAM[o];
      afL[i] = *(const short8*)&LAL[o];
    }
#pragma unroll
    for (int j = 0; j < 4; ++j) {
      int row = wn + j * 16 + lc;
      int o = row * 32 + ((lr + lc + (lc >> 2)) & 3) * 8;
      short8 bh = *(const short8*)&LWH[o];
      short8 bm = *(const short8*)&LWM[o];
      short8 bl = *(const short8*)&LWL[o];
#pragma unroll
      for (int i = 0; i < 4; ++i) {
        acc[i][j] = __builtin_amdgcn_mfma_f32_16x16x32_bf16(afM[i], bm, acc[i][j], 0, 0, 0);
        acc[i][j] = __builtin_amdgcn_mfma_f32_16x16x32_bf16(afL[i], bh, acc[i][j], 0, 0, 0);
        acc[i][j] = __builtin_amdgcn_mfma_f32_16x16x32_bf16(afH[i], bl, acc[i][j], 0, 0, 0);
        acc[i][j] = __builtin_amdgcn_mfma_f32_16x16x32_bf16(afM[i], bh, acc[i][j], 0, 0, 0);
        acc[i][j] = __builtin_amdgcn_mfma_f32_16x16x32_bf16(afH[i], bm, acc[i][j], 0, 0, 0);
        acc[i][j] = __builtin_amdgcn_mfma_f32_16x16x32_bf16(afH[i], bh, acc[i][j], 0, 0, 0);
      }
    }
    __syncthreads();
  }
  // Epilogue: channel-major, m = pixel, n = out-channel.
#pragma unroll
  for (int j = 0; j < 4; ++j) {
    int n = o0 + wn + j * 16 + lc;
    float bn_ = bias[n];
    size_t rowb = ((size_t)(b0 + z) * CCH + n) * HWP + p0;
#pragma unroll
    for (int i = 0; i < 4; ++i) {
      int m = wm + i * 16 + lr * 4;
      if (MODE == 0) {
        float4 o;
        o.x = acc[i][j][0] + bn_; o.y = acc[i][j][1] + bn_;
        o.z = acc[i][j][2] + bn_; o.w = acc[i][j][3] + bn_;
        *(float4*)(outF + rowb + m) = o;
      } else if (MODE == 1) {
        uchar4 o;
        o.x = (acc[i][j][0] + bn_ >= 2.0f) ? 1 : 0;
        o.y = (acc[i][j][1] + bn_ >= 2.0f) ? 1 : 0;
        o.z = (acc[i][j][2] + bn_ >= 2.0f) ? 1 : 0;
        o.w = (acc[i][j][3] + bn_ >= 2.0f) ? 1 : 0;
        *(uchar4*)(outB + rowb + m) = o;
      } else {
        u16x4 vh, vm2, vl2;
#pragma unroll
        for (int r = 0; r < 4; ++r) {
          u16 hh, mm, ll;
          split3(acc[i][j][r] + bn_, hh, mm, ll);
          vh[r] = hh; vm2[r] = mm; vl2[r] = ll;
        }
        *(u16x4*)(outH + rowb + m) = vh;
        *(u16x4*)(outM + rowb + m) = vm2;
        *(u16x4*)(outL + rowb + m) = vl2;
      }
    }
  }
}

// ---------------------------------------------------------------------------
// Attention per (z,c): Q and K arrive PRE-SPLIT (3 bf16 planes each, from
// gemm2s MODE 2) -- no split3 in the staging path at all.
// 320 threads: wave = m-tile. LDS row stride 104 u16 (2-way b128 reads).
// ---------------------------------------------------------------------------
__global__ __launch_bounds__(320) void attn_k(
    const u16* __restrict__ qh_g, const u16* __restrict__ qm_g, const u16* __restrict__ ql_g,
    const u16* __restrict__ kh_g, const u16* __restrict__ km_g, const u16* __restrict__ kl_g,
    const u8* __restrict__ vv, u8* __restrict__ s)
{
  __shared__ alignas(16) u16 L[24960];   // K 3-split [h'][w]; overlaid by S 3-split [h][h']
  __shared__ alignas(16) u8  VT[8320];   // V^T [u][h'] stride 104
  const int tid = threadIdx.x, wave = tid >> 6, lane = tid & 63;
  const int lc = lane & 15, lr = lane >> 4;
  const size_t off = (size_t)blockIdx.x * HWP;
  u16* KH = L; u16* KM = L + 8320; u16* KL = L + 16640;

  // Hoist Q fragments: row h = wave*16+lc, k-cols w0..w0+7.
  short8 qfr[3][3];  // [kc][h/m/l]
  const int hrow = wave * 16 + lc;
#pragma unroll
  for (int kc = 0; kc < 3; ++kc) {
    int w0 = kc * 32 + lr * 8;
    if (w0 < 80) {
      size_t qo = off + (size_t)hrow * 80 + w0;
      qfr[kc][0] = *(const short8*)(qh_g + qo);
      qfr[kc][1] = *(const short8*)(qm_g + qo);
      qfr[kc][2] = *(const short8*)(ql_g + qo);
    } else {
      qfr[kc][0] = (short8){0, 0, 0, 0, 0, 0, 0, 0};
      qfr[kc][1] = qfr[kc][0];
      qfr[kc][2] = qfr[kc][0];
    }
  }

  // Stage K 3-split planes: 12 granules/row (10 data + 2 zero pad), 80 rows.
#pragma unroll
  for (int t = 0; t < 3; ++t) {
    int g = t * 320 + tid;            // 0..959
    int h = g / 12, wc = g - h * 12;
    int dst = h * 104 + wc * 8;
    if (wc < 10) {
      size_t so = off + (size_t)h * 80 + wc * 8;
      *(short8*)&KH[dst] = *(const short8*)(kh_g + so);
      *(short8*)&KM[dst] = *(const short8*)(km_g + so);
      *(short8*)&KL[dst] = *(const short8*)(kl_g + so);
    } else {
      short8 z8 = (short8){0, 0, 0, 0, 0, 0, 0, 0};
      *(short8*)&KH[dst] = z8; *(short8*)&KM[dst] = z8; *(short8*)&KL[dst] = z8;
    }
  }
  // VT pads (cols 80..95): 80 rows x 4 dwords, exactly 320 threads.
  {
    int row = tid >> 2, qq = tid & 3;
    *(u32*)&VT[row * 104 + 80 + qq * 4] = 0;
  }
  // VT transpose stage: uchar4 reads, byte scatter.
#pragma unroll
  for (int t = 0; t < 5; ++t) {
    int q = t * 320 + tid;            // 0..1599 quads
    int h = q / 20, w4 = (q - h * 20) * 4;
    uchar4 v4 = *(const uchar4*)(vv + off + (size_t)h * 80 + w4);
    VT[(w4 + 0) * 104 + h] = v4.x;
    VT[(w4 + 1) * 104 + h] = v4.y;
    VT[(w4 + 2) * 104 + h] = v4.z;
    VT[(w4 + 3) * 104 + h] = v4.w;
  }
  __syncthreads();

  // Stage 1: S = Q K^T.  m-rows h = wave*16+lc, k = w (pad 96), n = h'.
  f32x4 accS[5];
#pragma unroll
  for (int n = 0; n < 5; ++n) accS[n] = (f32x4){0.f, 0.f, 0.f, 0.f};
  for (int kc = 0; kc < 3; ++kc) {
#pragma unroll
    for (int n = 0; n < 5; ++n) {
      int bo = (n * 16 + lc) * 104 + kc * 32 + lr * 8;
      short8 kh_ = *(const short8*)&KH[bo];
      short8 km_ = *(const short8*)&KM[bo];
      short8 kl_ = *(const short8*)&KL[bo];
      __builtin_amdgcn_s_setprio(1);
      accS[n] = __builtin_amdgcn_mfma_f32_16x16x32_bf16(qfr[kc][0], kl_, accS[n], 0, 0, 0);
      accS[n] = __builtin_amdgcn_mfma_f32_16x16x32_bf16(qfr[kc][2], kh_, accS[n], 0, 0, 0);
      accS[n] = __builtin_amdgcn_mfma_f32_16x16x32_bf16(qfr[kc][1], km_, accS[n], 0, 0, 0);
      accS[n] = __builtin_amdgcn_mfma_f32_16x16x32_bf16(qfr[kc][1], kh_, accS[n], 0, 0, 0);
      accS[n] = __builtin_amdgcn_mfma_f32_16x16x32_bf16(qfr[kc][0], km_, accS[n], 0, 0, 0);
      accS[n] = __builtin_amdgcn_mfma_f32_16x16x32_bf16(qfr[kc][0], kh_, accS[n], 0, 0, 0);
      __builtin_amdgcn_s_setprio(0);
    }
  }
  __syncthreads();   // all K reads done; L becomes S (pads stay zero)
#pragma unroll
  for (int n = 0; n < 5; ++n) {
#pragma unroll
    for (int r = 0; r < 4; ++r) {
      u16 hh, mm, ll; split3(accS[n][r], hh, mm, ll);
      int o = (wave * 16 + lr * 4 + r) * 104 + n * 16 + lc;
      KH[o] = hh; KM[o] = mm; KL[o] = ll;
    }
  }
  __syncthreads();
  // Stage 2: attn = S V ; spike at raw >= 8  (attn*0.125 >= 1)
  f32x4 accA[5];
#pragma unroll
  for (int n = 0; n < 5; ++n) accA[n] = (f32x4){0.f, 0.f, 0.f, 0.f};
  for (int kc = 0; kc < 3; ++kc) {
    int ao = (wave * 16 + lc) * 104 + kc * 32 + lr * 8;
    short8 sh_ = *(const short8*)&KH[ao];
    short8 sm_ = *(const short8*)&KM[ao];
    short8 sl_ = *(const short8*)&KL[ao];
#pragma unroll
    for (int n = 0; n < 5; ++n) {
      const u8* vp = &VT[(n * 16 + lc) * 104 + kc * 32 + lr * 8];
      u32 b0 = *(const u32*)vp;
      u32 b1 = *(const u32*)(vp + 4);
      u32 e0 = ((b0 & 255u) ? 0x3F80u : 0u) | (((b0 >> 8) & 255u) ? 0x3F800000u : 0u);
      u32 e1 = (((b0 >> 16) & 255u) ? 0x3F80u : 0u) | (((b0 >> 24) & 255u) ? 0x3F800000u : 0u);
      u32 e2 = ((b1 & 255u) ? 0x3F80u : 0u) | (((b1 >> 8) & 255u) ? 0x3F800000u : 0u);
      u32 e3 = (((b1 >> 16) & 255u) ? 0x3F80u : 0u) | (((b1 >> 24) & 255u) ? 0x3F800000u : 0u);
      u32 vbw[4] = {e0, e1, e2, e3};
      short8 vb = *(const short8*)vbw;
      __builtin_amdgcn_s_setprio(1);
      accA[n] = __builtin_amdgcn_mfma_f32_16x16x32_bf16(sl_, vb, accA[n], 0, 0, 0);
      accA[n] = __builtin_amdgcn_mfma_f32_16x16x32_bf16(sm_, vb, accA[n], 0, 0, 0);
      accA[n] = __builtin_amdgcn_mfma_f32_16x16x32_bf16(sh_, vb, accA[n], 0, 0, 0);
      __builtin_amdgcn_s_setprio(0);
    }
  }
#pragma unroll
  for (int n = 0; n < 5; ++n)
#pragma unroll
    for (int r = 0; r < 4; ++r)
      s[off + (size_t)(wave * 16 + lr * 4 + r) * 80 + n * 16 + lc] =
          (accA[n][r] >= 8.0f) ? 1 : 0;
}

// ---------------------------------------------------------------------------
extern "C" void kernel_launch(void* const* d_in, const int* in_sizes, int n_in,
                              void* d_out, int out_size, void* d_ws, size_t ws_size,
                              hipStream_t stream)
{
  const float* x   = (const float*)d_in[0];
  const float* w1  = (const float*)d_in[1];
  const float* dwk = (const float*)d_in[2];
  const float* w2  = (const float*)d_in[3];
  const float* bnp = (const float*)d_in[4];
  float* out = (float*)d_out;
  char* ws = (char*)d_ws;

  // Workspace layout (~292 MB total, unchanged size).
  u16* W1H = (u16*)(ws + 0);
  u16* W1M = (u16*)(ws + 524288);
  u16* W1L = (u16*)(ws + 1048576);
  u16* W2H = (u16*)(ws + 1572864);
  u16* W2M = (u16*)(ws + 2097152);
  u16* W2L = (u16*)(ws + 2621440);
  float* B0F = (float*)(ws + 3145728);
  float* B2F = (float*)(ws + 3149824);
  u8*    SPM = (u8*)(ws + 3153920);          // s pixel-major, full 16 batches
  u8*    XS  = (u8*)(ws + 29368320);         // xs, half-batch chunk
  float* T1  = (float*)(ws + 42475520);      // fp32 branch tmp, half chunk
  u16*   KH_ = (u16*)(ws + 42475520);        // overlays T1 (T1 dead at write time)
  u16*   KM_ = (u16*)(ws + 68689920);
  u16*   QH_ = (u16*)(ws + 94904320);        // old QF region start
  u16*   QM_ = (u16*)(ws + 121118720);
  u16*   QL_ = (u16*)(ws + 147333120);
  u16*   KL_ = (u16*)(ws + 173547520);       // old KF region tail
  u8*    V   = (u8*)(ws + 199761920);        // v binary CM (s_cm in-place)
  u16*   D2H = (u16*)(ws + 212869120);       // dw split hi, pixel-major
  u16*   D2M = (u16*)(ws + 239083520);
  u16*   D2L = (u16*)(ws + 265297920);       // ends 291512320

  dim3 gb(256);
  fold_weights<<<dim3(1024), gb, 0, stream>>>(w1, w2, bnp,
      W1H, W1M, W1L, W2H, W2M, W2L, B0F, B2F);

  for (int c = 0; c < 2; ++c) {
    int b0 = c * 8;
    dim3 gh(100, 4, 8), gg(50, 2, 8), gd(100, 4, 8);
    head_spike<<<gh, gb, 0, stream>>>(x, XS, b0);
    // v branch (binary spike epilogue) -- first, so T1 is free for K planes later
    gemm1<<<gg, gb, 0, stream>>>(XS, 0, W1H + 2 * 65536, W1M + 2 * 65536, W1L + 2 * 65536,
                                 B0F + 512, T1);
    dw3<<<gd, gb, 0, stream>>>(T1, dwk + 2 * 2304, D2H, D2M, D2L);
    gemm2s<1><<<gg, gb, 0, stream>>>(D2H, D2M, D2L,
                                     W2H + 2 * 65536, W2M + 2 * 65536, W2L + 2 * 65536,
                                     B2F + 512, 0, nullptr, V, nullptr, nullptr, nullptr);
    // q branch -> pre-split planes
    gemm1<<<gg, gb, 0, stream>>>(XS, 0, W1H + 0 * 65536, W1M + 0 * 65536, W1L + 0 * 65536,
                                 B0F + 0, T1);
    dw3<<<gd, gb, 0, stream>>>(T1, dwk + 0 * 2304, D2H, D2M, D2L);
    gemm2s<2><<<gg, gb, 0, stream>>>(D2H, D2M, D2L,
                                     W2H + 0 * 65536, W2M + 0 * 65536, W2L + 0 * 65536,
                                     B2F + 0, 0, nullptr, nullptr, QH_, QM_, QL_);
    // k branch -> pre-split planes (KH_/KM_ overlay T1, which is dead by then)
    gemm1<<<gg, gb, 0, stream>>>(XS, 0, W1H + 1 * 65536, W1M + 1 * 65536, W1L + 1 * 65536,
                                 B0F + 256, T1);
    dw3<<<gd, gb, 0, stream>>>(T1, dwk + 1 * 2304, D2H, D2M, D2L);
    gemm2s<2><<<gg, gb, 0, stream>>>(D2H, D2M, D2L,
                                     W2H + 1 * 65536, W2M + 1 * 65536, W2L + 1 * 65536,
                                     B2F + 256, 0, nullptr, nullptr, KH_, KM_, KL_);
    // attention -> s channel-major (in-place over V), then to pixel-major SPM
    attn_k<<<dim3(2048), dim3(320), 0, stream>>>(QH_, QM_, QL_, KH_, KM_, KL_, V, V);
    transpose_s<<<gh, gb, 0, stream>>>(V, SPM, b0);
  }
  // proj branch -> fp32 d_out (channel-major), chunked to fit T1
  for (int c = 0; c < 2; ++c) {
    int b0 = c * 8;
    dim3 gg(50, 2, 8), gd(100, 4, 8);
    gemm1<<<gg, gb, 0, stream>>>(SPM, b0, W1H + 3 * 65536, W1M + 3 * 65536, W1L + 3 * 65536,
                                 B0F + 768, T1);
    dw3<<<gd, gb, 0, stream>>>(T1, dwk + 3 * 2304, D2H, D2M, D2L);
    gemm2s<0><<<gg, gb, 0, stream>>>(D2H, D2M, D2L,
                                     W2H + 3 * 65536, W2M + 3 * 65536, W2L + 3 * 65536,
                                     B2F + 768, b0, out, nullptr, nullptr, nullptr, nullptr);
  }
}